// Round 3
// baseline (338.853 us; speedup 1.0000x reference)
//
#include <hip/hip_runtime.h>
#include <hip/hip_bf16.h>

// MHA: out = softmax((x@Wq^T)(x@Wk^T)^T / sqrt(D)) (x@Wv^T) @ Wo^T
// B=2, S=2048, E=1024, H=16, D=64.

typedef __attribute__((ext_vector_type(8))) short short8;
typedef __attribute__((ext_vector_type(4))) float f32x4;
typedef __attribute__((ext_vector_type(4))) unsigned short us4;

#define MFMA16(a, b, c) __builtin_amdgcn_mfma_f32_16x16x32_bf16(a, b, c, 0, 0, 0)

static constexpr int B = 2;
static constexpr int S = 2048;
static constexpr int E = 1024;
static constexpr int H = 16;
static constexpr int D = 64;
static constexpr int M = B * S;               // 4096 rows in projection GEMMs
static constexpr size_t NE = (size_t)M * E;   // activation elements
static constexpr size_t NW = (size_t)E * E;   // weight elements

// round-to-nearest-even fp32 -> bf16 (bit pattern as ushort)
static __device__ __forceinline__ unsigned short f2bf(float x) {
  unsigned int u = __float_as_uint(x);
  unsigned int r = (u + 0x7FFFu + ((u >> 16) & 1u)) >> 16;
  return (unsigned short)r;
}

// async global -> LDS, 16B per lane. LDS dest = wave-uniform base + lane*16.
static __device__ __forceinline__ void gload_lds16(const unsigned short* g,
                                                   unsigned short* l) {
  __builtin_amdgcn_global_load_lds(
      (const __attribute__((address_space(1))) unsigned int*)g,
      (__attribute__((address_space(3))) unsigned int*)l, 16, 0, 0);
}

// ---------------- fp32 -> bf16 conversion (fused, z-indexed) --------------
__global__ void cvt_act_kernel(const float* __restrict__ s0,
                               const float* __restrict__ s1,
                               const float* __restrict__ s2,
                               unsigned short* __restrict__ d0,
                               unsigned short* __restrict__ d1,
                               unsigned short* __restrict__ d2, int n4) {
  const float* src = (blockIdx.y == 0) ? s0 : ((blockIdx.y == 1) ? s1 : s2);
  unsigned short* dst = (blockIdx.y == 0) ? d0 : ((blockIdx.y == 1) ? d1 : d2);
  for (int i = blockIdx.x * blockDim.x + threadIdx.x; i < n4;
       i += gridDim.x * blockDim.x) {
    float4 v = reinterpret_cast<const float4*>(src)[i];
    ushort4 o;
    o.x = f2bf(v.x); o.y = f2bf(v.y); o.z = f2bf(v.z); o.w = f2bf(v.w);
    reinterpret_cast<ushort4*>(dst)[i] = o;
  }
}

__global__ void cvt_w_kernel(const float* __restrict__ s0,
                             const float* __restrict__ s1,
                             const float* __restrict__ s2,
                             const float* __restrict__ s3,
                             unsigned short* __restrict__ d0,
                             unsigned short* __restrict__ d1,
                             unsigned short* __restrict__ d2,
                             unsigned short* __restrict__ d3, int n4) {
  const int z = blockIdx.y;
  const float* src = (z == 0) ? s0 : ((z == 1) ? s1 : ((z == 2) ? s2 : s3));
  unsigned short* dst = (z == 0) ? d0 : ((z == 1) ? d1 : ((z == 2) ? d2 : d3));
  for (int i = blockIdx.x * blockDim.x + threadIdx.x; i < n4;
       i += gridDim.x * blockDim.x) {
    float4 v = reinterpret_cast<const float4*>(src)[i];
    ushort4 o;
    o.x = f2bf(v.x); o.y = f2bf(v.y); o.z = f2bf(v.z); o.w = f2bf(v.w);
    reinterpret_cast<ushort4*>(dst)[i] = o;
  }
}

// ---------------- 128x128-tile GEMM: out = A @ W^T (m97 structure) --------
// A: [M][E] bf16. W: [N=E][E] bf16 (row = out col). BK=32, 4 waves 2x2,
// global_load_lds width-16 staging, 2 barriers per K-step.
// MODE 0: Q -> Qh[B][H][S][D] * 0.125   MODE 1: K -> Kh[B][H][S][D]
// MODE 2: V -> Vt[B][H][D][S]           MODE 3: fp32 row-major out
template <int MODE>
__global__ __launch_bounds__(256) void gemm128_kernel(
    const unsigned short* __restrict__ A, const unsigned short* __restrict__ W,
    unsigned short* __restrict__ obf, float* __restrict__ of32) {
  __shared__ __align__(16) unsigned short As[128 * 32];
  __shared__ __align__(16) unsigned short Bs[128 * 32];

  const int wave = threadIdx.x >> 6;
  const int lane = threadIdx.x & 63;
  const int lr = lane & 15;
  const int lk = (lane >> 4) * 8;
  const int m0 = blockIdx.x * 128;
  const int n0 = blockIdx.y * 128;
  const int wm = (wave >> 1) * 64;
  const int wn = (wave & 1) * 64;
  const int srow = lane >> 2;        // row within 16-row staging chunk
  const int scol = (lane & 3) * 8;   // element col within BK=32

  f32x4 acc[4][4];
  const f32x4 fz = {0.f, 0.f, 0.f, 0.f};
#pragma unroll
  for (int i = 0; i < 4; ++i)
#pragma unroll
    for (int j = 0; j < 4; ++j) acc[i][j] = fz;

  for (int kk = 0; kk < E; kk += 32) {
    // stage A[128][32], B[128][32]; chunk c = 16 rows = 1KB = one wave issue
#pragma unroll
    for (int i = 0; i < 2; ++i) {
      const int c = wave * 2 + i;
      const int row = c * 16 + srow;
      gload_lds16(A + (size_t)(m0 + row) * E + kk + scol, &As[c * 512]);
      gload_lds16(W + (size_t)(n0 + row) * E + kk + scol, &Bs[c * 512]);
    }
    __syncthreads();  // drains vmcnt(0): LDS tiles ready
    short8 af[4], bw[4];
#pragma unroll
    for (int i = 0; i < 4; ++i)
      af[i] = *reinterpret_cast<const short8*>(&As[(wm + i * 16 + lr) * 32 + lk]);
#pragma unroll
    for (int j = 0; j < 4; ++j)
      bw[j] = *reinterpret_cast<const short8*>(&Bs[(wn + j * 16 + lr) * 32 + lk]);
#pragma unroll
    for (int i = 0; i < 4; ++i)
#pragma unroll
      for (int j = 0; j < 4; ++j) acc[i][j] = MFMA16(af[i], bw[j], acc[i][j]);
    __syncthreads();  // reads done before next stage overwrites
  }

  const int rbase = (lane >> 4) * 4;
#pragma unroll
  for (int i = 0; i < 4; ++i) {
#pragma unroll
    for (int j = 0; j < 4; ++j) {
      const int col = n0 + wn + j * 16 + lr;
#pragma unroll
      for (int r = 0; r < 4; ++r) {
        const int row = m0 + wm + i * 16 + rbase + r;
        const float v = acc[i][j][r];
        if (MODE == 0) {
          const int h = col >> 6, d = col & 63, b = row >> 11, s = row & (S - 1);
          obf[(((size_t)b * H + h) * S + s) * D + d] = f2bf(v * 0.125f);
        } else if (MODE == 1) {
          const int h = col >> 6, d = col & 63, b = row >> 11, s = row & (S - 1);
          obf[(((size_t)b * H + h) * S + s) * D + d] = f2bf(v);
        } else if (MODE == 2) {
          const int h = col >> 6, d = col & 63, b = row >> 11, s = row & (S - 1);
          obf[(((size_t)b * H + h) * D + d) * S + s] = f2bf(v);
        } else {
          of32[(size_t)row * E + col] = v;
        }
      }
    }
  }
}

// ---------------- flash attention (swapped-operand, KV-split) -------------
// grid: (S/32, B*H), 4 waves/block. Wave = (qg, half): qg owns 16 q-rows,
// half owns keys [half*S/2, (half+1)*S/2). Swapped MFMA: QK^T = mfma(K,Q)
// -> C col = q (lane&15), row = key -> each lane owns ONE q-row, 16 scores
// in-register -> softmax stats are in-lane + 2 shfl. PV = mfma(V^T, P^T)
// -> acc col = q, row = d. Halves merge (m,l,acc) via LDS at the end.
// Qh pre-scaled by 1/sqrt(D). Vt is [B][H][D][S].
__global__ __launch_bounds__(256) void attn_kernel(
    const unsigned short* __restrict__ Qh, const unsigned short* __restrict__ Kh,
    const unsigned short* __restrict__ Vt, unsigned short* __restrict__ Xb) {
  __shared__ __align__(16) unsigned short Plds[4][16 * 72];  // row pad 64->72
  __shared__ float Mrg[2][64][18];  // [qg][lane][16 acc + m + l]

  const int wave = threadIdx.x >> 6;
  const int lane = threadIdx.x & 63;
  const int lr = lane & 15;       // q index within 16
  const int jj = lane >> 4;       // k-fragment group (0..3)
  const int lk = jj * 8;
  const int qg = wave >> 1;
  const int half = wave & 1;
  const int bh = blockIdx.y;
  const int q0 = blockIdx.x * 32 + qg * 16;
  constexpr int S2 = S / 2;

  const unsigned short* Qp = Qh + ((size_t)bh * S + q0) * D;
  short8 qf0 = *reinterpret_cast<const short8*>(Qp + (size_t)lr * D + lk);
  short8 qf1 = *reinterpret_cast<const short8*>(Qp + (size_t)lr * D + 32 + lk);

  const f32x4 fz = {0.f, 0.f, 0.f, 0.f};
  float mrun = -3.0e38f, lsum = 0.f;
  f32x4 acc[4];
#pragma unroll
  for (int dt = 0; dt < 4; ++dt) acc[dt] = fz;

  const unsigned short* Vbase = Vt + (size_t)bh * D * S;
  unsigned short* Pw = &Plds[wave][0];

  const int kbeg = half * S2;
  for (int kt = kbeg; kt < kbeg + S2; kt += 64) {
    const unsigned short* Kp = Kh + ((size_t)bh * S + kt) * D;
    f32x4 sf[4];
    __builtin_amdgcn_s_setprio(1);
#pragma unroll
    for (int nt = 0; nt < 4; ++nt) {
      const unsigned short* kr = Kp + (size_t)(nt * 16 + lr) * D + lk;
      short8 kf0 = *reinterpret_cast<const short8*>(kr);
      short8 kf1 = *reinterpret_cast<const short8*>(kr + 32);
      f32x4 z = fz;
      z = MFMA16(kf0, qf0, z);   // swapped: col=q, row=key
      z = MFMA16(kf1, qf1, z);
      sf[nt] = z;                // sf[nt][r]: key = nt*16 + 4*jj + r, q = lr
    }
    __builtin_amdgcn_s_setprio(0);

    // V fragment loads issued early: latency hides under softmax VALU
    short8 vf0[4], vf1[4];
#pragma unroll
    for (int dt = 0; dt < 4; ++dt) {
      const unsigned short* vr = Vbase + (size_t)(dt * 16 + lr) * S + kt + lk;
      vf0[dt] = *reinterpret_cast<const short8*>(vr);
      vf1[dt] = *reinterpret_cast<const short8*>(vr + 32);
    }

    // in-lane softmax for q=lr over this lane's 16 keys, then 2-shfl combine
    float mx = sf[0][0];
#pragma unroll
    for (int nt = 0; nt < 4; ++nt)
#pragma unroll
      for (int r = 0; r < 4; ++r) mx = fmaxf(mx, sf[nt][r]);
    mx = fmaxf(mx, __shfl_xor(mx, 16));
    mx = fmaxf(mx, __shfl_xor(mx, 32));
    const float nm = fmaxf(mrun, mx);
    const float fac = __expf(mrun - nm);
    mrun = nm;
    float p[4][4];
    float rs = 0.f;
#pragma unroll
    for (int nt = 0; nt < 4; ++nt)
#pragma unroll
      for (int r = 0; r < 4; ++r) {
        p[nt][r] = __expf(sf[nt][r] - nm);
        rs += p[nt][r];
      }
    rs += __shfl_xor(rs, 16);
    rs += __shfl_xor(rs, 32);
    lsum = lsum * fac + rs;
#pragma unroll
    for (int dt = 0; dt < 4; ++dt)
#pragma unroll
      for (int r = 0; r < 4; ++r) acc[dt][r] *= fac;

    // P^T re-layout: lane holds 4 consecutive keys per nt -> packed b64
    // writes into row-padded [16][72] (2-way banks, free).
#pragma unroll
    for (int nt = 0; nt < 4; ++nt) {
      us4 w;
      w.x = f2bf(p[nt][0]); w.y = f2bf(p[nt][1]);
      w.z = f2bf(p[nt][2]); w.w = f2bf(p[nt][3]);
      *reinterpret_cast<us4*>(&Pw[lr * 72 + nt * 16 + 4 * jj]) = w;
    }
    // wave-local ordering: DS pipe is in-order per wave; fence the compiler
    __builtin_amdgcn_sched_barrier(0);
    asm volatile("s_waitcnt lgkmcnt(0)" ::: "memory");
    __builtin_amdgcn_sched_barrier(0);
    short8 pa0 = *reinterpret_cast<const short8*>(&Pw[lr * 72 + 8 * jj]);
    short8 pa1 = *reinterpret_cast<const short8*>(&Pw[lr * 72 + 32 + 8 * jj]);
    __builtin_amdgcn_wave_barrier();  // keep reads ahead of next-iter writes

    __builtin_amdgcn_s_setprio(1);
#pragma unroll
    for (int dt = 0; dt < 4; ++dt) {
      acc[dt] = MFMA16(vf0[dt], pa0, acc[dt]);  // swapped: col=q, row=d
      acc[dt] = MFMA16(vf1[dt], pa1, acc[dt]);
    }
    __builtin_amdgcn_s_setprio(0);
  }

  // merge the two KV-halves of each q-group
  if (half == 1) {
#pragma unroll
    for (int dt = 0; dt < 4; ++dt)
#pragma unroll
      for (int r = 0; r < 4; ++r) Mrg[qg][lane][dt * 4 + r] = acc[dt][r];
    Mrg[qg][lane][16] = mrun;
    Mrg[qg][lane][17] = lsum;
  }
  __syncthreads();
  if (half == 0) {
    const float mo = Mrg[qg][lane][16];
    const float lo = Mrg[qg][lane][17];
    const float nm = fmaxf(mrun, mo);
    const float fa = __expf(mrun - nm);
    const float fb = __expf(mo - nm);
    const float inv = 1.0f / (lsum * fa + lo * fb);
    const int b = bh >> 4, h = bh & (H - 1);
    const int row = q0 + lr;
#pragma unroll
    for (int dt = 0; dt < 4; ++dt) {
#pragma unroll
      for (int r = 0; r < 4; ++r) {
        const int d = dt * 16 + 4 * jj + r;
        const float o = (acc[dt][r] * fa + Mrg[qg][lane][dt * 4 + r] * fb) * inv;
        Xb[((size_t)b * S + row) * E + h * D + d] = f2bf(o);
      }
    }
  }
}

extern "C" void kernel_launch(void* const* d_in, const int* in_sizes, int n_in,
                              void* d_out, int out_size, void* d_ws, size_t ws_size,
                              hipStream_t stream) {
  const float* q_f = (const float*)d_in[0];
  const float* k_f = (const float*)d_in[1];
  const float* v_f = (const float*)d_in[2];
  const float* wq_f = (const float*)d_in[3];
  const float* wk_f = (const float*)d_in[4];
  const float* wv_f = (const float*)d_in[5];
  const float* wo_f = (const float*)d_in[6];

  // workspace layout (bf16 halves): 7*NE + 4*NW elements = 64 MB
  unsigned short* xq = (unsigned short*)d_ws;
  unsigned short* xk = xq + NE;
  unsigned short* xv = xk + NE;
  unsigned short* wq = xv + NE;
  unsigned short* wk = wq + NW;
  unsigned short* wv = wk + NW;
  unsigned short* wo = wv + NW;
  unsigned short* Qh = wo + NW;
  unsigned short* Kh = Qh + NE;
  unsigned short* Vt = Kh + NE;
  unsigned short* Xb = Vt + NE;

  // 1) convert inputs + weights to bf16 (2 fused launches)
  cvt_act_kernel<<<dim3(512, 3), 256, 0, stream>>>(q_f, k_f, v_f, xq, xk, xv,
                                                   (int)(NE / 4));
  cvt_w_kernel<<<dim3(256, 4), 256, 0, stream>>>(wq_f, wk_f, wv_f, wo_f, wq, wk,
                                                 wv, wo, (int)(NW / 4));

  // 2) Q/K/V projections
  gemm128_kernel<0><<<dim3(M / 128, E / 128), 256, 0, stream>>>(xq, wq, Qh, nullptr);
  gemm128_kernel<1><<<dim3(M / 128, E / 128), 256, 0, stream>>>(xk, wk, Kh, nullptr);
  gemm128_kernel<2><<<dim3(M / 128, E / 128), 256, 0, stream>>>(xv, wv, Vt, nullptr);

  // 3) flash attention (swapped-operand, KV-split 2-way)
  attn_kernel<<<dim3(S / 32, B * H), 256, 0, stream>>>(Qh, Kh, Vt, Xb);

  // 4) output projection (fp32 out)
  gemm128_kernel<3><<<dim3(M / 128, E / 128), 256, 0, stream>>>(Xb, wo, nullptr,
                                                                (float*)d_out);
}

// Round 4
// 195.615 us; speedup vs baseline: 1.7322x; 1.7322x over previous
//
#include <hip/hip_runtime.h>
#include <hip/hip_bf16.h>

// MHA: out = softmax((x@Wq^T)(x@Wk^T)^T / sqrt(D)) (x@Wv^T) @ Wo^T
// B=2, S=2048, E=1024, H=16, D=64.

typedef __attribute__((ext_vector_type(8))) short short8;
typedef __attribute__((ext_vector_type(4))) float f32x4;
typedef __attribute__((ext_vector_type(4))) unsigned short us4;

#define MFMA16(a, b, c) __builtin_amdgcn_mfma_f32_16x16x32_bf16(a, b, c, 0, 0, 0)

static constexpr int B = 2;
static constexpr int S = 2048;
static constexpr int E = 1024;
static constexpr int H = 16;
static constexpr int D = 64;
static constexpr int M = B * S;               // 4096 rows in projection GEMMs
static constexpr size_t NE = (size_t)M * E;   // activation elements
static constexpr size_t NW = (size_t)E * E;   // weight elements

// round-to-nearest-even fp32 -> bf16 (bit pattern as ushort)
static __device__ __forceinline__ unsigned short f2bf(float x) {
  unsigned int u = __float_as_uint(x);
  unsigned int r = (u + 0x7FFFu + ((u >> 16) & 1u)) >> 16;
  return (unsigned short)r;
}

// async global -> LDS, 16B per lane. LDS dest = wave-uniform base + lane*16.
static __device__ __forceinline__ void gload_lds16(const unsigned short* g,
                                                   unsigned short* l) {
  __builtin_amdgcn_global_load_lds(
      (const __attribute__((address_space(1))) unsigned int*)g,
      (__attribute__((address_space(3))) unsigned int*)l, 16, 0, 0);
}

// ---------------- fp32 -> bf16 conversion (fused, z-indexed) --------------
__global__ void cvt_act_kernel(const float* __restrict__ s0,
                               const float* __restrict__ s1,
                               const float* __restrict__ s2,
                               unsigned short* __restrict__ d0,
                               unsigned short* __restrict__ d1,
                               unsigned short* __restrict__ d2, int n4) {
  const float* src = (blockIdx.y == 0) ? s0 : ((blockIdx.y == 1) ? s1 : s2);
  unsigned short* dst = (blockIdx.y == 0) ? d0 : ((blockIdx.y == 1) ? d1 : d2);
  for (int i = blockIdx.x * blockDim.x + threadIdx.x; i < n4;
       i += gridDim.x * blockDim.x) {
    float4 v = reinterpret_cast<const float4*>(src)[i];
    ushort4 o;
    o.x = f2bf(v.x); o.y = f2bf(v.y); o.z = f2bf(v.z); o.w = f2bf(v.w);
    reinterpret_cast<ushort4*>(dst)[i] = o;
  }
}

__global__ void cvt_w_kernel(const float* __restrict__ s0,
                             const float* __restrict__ s1,
                             const float* __restrict__ s2,
                             const float* __restrict__ s3,
                             unsigned short* __restrict__ d0,
                             unsigned short* __restrict__ d1,
                             unsigned short* __restrict__ d2,
                             unsigned short* __restrict__ d3, int n4) {
  const int z = blockIdx.y;
  const float* src = (z == 0) ? s0 : ((z == 1) ? s1 : ((z == 2) ? s2 : s3));
  unsigned short* dst = (z == 0) ? d0 : ((z == 1) ? d1 : ((z == 2) ? d2 : d3));
  for (int i = blockIdx.x * blockDim.x + threadIdx.x; i < n4;
       i += gridDim.x * blockDim.x) {
    float4 v = reinterpret_cast<const float4*>(src)[i];
    ushort4 o;
    o.x = f2bf(v.x); o.y = f2bf(v.y); o.z = f2bf(v.z); o.w = f2bf(v.w);
    reinterpret_cast<ushort4*>(dst)[i] = o;
  }
}

// ---------------- 128x128-tile GEMM: out = A @ W^T (m97 structure) --------
// A: [M][E] bf16. W: [N=E][E] bf16 (row = out col). BK=32, 4 waves 2x2,
// global_load_lds width-16 staging, 2 barriers per K-step.
// MODE 0: Q -> Qh[B][H][S][D] * 0.125   MODE 1: K -> Kh[B][H][S][D]
// MODE 2: V -> Vt[B][H][D][S]           MODE 3: fp32 row-major out
template <int MODE>
__global__ __launch_bounds__(256) void gemm128_kernel(
    const unsigned short* __restrict__ A, const unsigned short* __restrict__ W,
    unsigned short* __restrict__ obf, float* __restrict__ of32) {
  __shared__ __align__(16) unsigned short As[128 * 32];
  __shared__ __align__(16) unsigned short Bs[128 * 32];

  const int wave = threadIdx.x >> 6;
  const int lane = threadIdx.x & 63;
  const int lr = lane & 15;
  const int lk = (lane >> 4) * 8;
  const int m0 = blockIdx.x * 128;
  const int n0 = blockIdx.y * 128;
  const int wm = (wave >> 1) * 64;
  const int wn = (wave & 1) * 64;
  const int srow = lane >> 2;        // row within 16-row staging chunk
  const int scol = (lane & 3) * 8;   // element col within BK=32

  f32x4 acc[4][4];
  const f32x4 fz = {0.f, 0.f, 0.f, 0.f};
#pragma unroll
  for (int i = 0; i < 4; ++i)
#pragma unroll
    for (int j = 0; j < 4; ++j) acc[i][j] = fz;

  for (int kk = 0; kk < E; kk += 32) {
    // stage A[128][32], B[128][32]; chunk c = 16 rows = 1KB = one wave issue
#pragma unroll
    for (int i = 0; i < 2; ++i) {
      const int c = wave * 2 + i;
      const int row = c * 16 + srow;
      gload_lds16(A + (size_t)(m0 + row) * E + kk + scol, &As[c * 512]);
      gload_lds16(W + (size_t)(n0 + row) * E + kk + scol, &Bs[c * 512]);
    }
    __syncthreads();  // drains vmcnt(0): LDS tiles ready
    short8 af[4], bw[4];
#pragma unroll
    for (int i = 0; i < 4; ++i)
      af[i] = *reinterpret_cast<const short8*>(&As[(wm + i * 16 + lr) * 32 + lk]);
#pragma unroll
    for (int j = 0; j < 4; ++j)
      bw[j] = *reinterpret_cast<const short8*>(&Bs[(wn + j * 16 + lr) * 32 + lk]);
#pragma unroll
    for (int i = 0; i < 4; ++i)
#pragma unroll
      for (int j = 0; j < 4; ++j) acc[i][j] = MFMA16(af[i], bw[j], acc[i][j]);
    __syncthreads();  // reads done before next stage overwrites
  }

  const int rbase = (lane >> 4) * 4;
#pragma unroll
  for (int i = 0; i < 4; ++i) {
#pragma unroll
    for (int j = 0; j < 4; ++j) {
      const int col = n0 + wn + j * 16 + lr;
#pragma unroll
      for (int r = 0; r < 4; ++r) {
        const int row = m0 + wm + i * 16 + rbase + r;
        const float v = acc[i][j][r];
        if (MODE == 0) {
          const int h = col >> 6, d = col & 63, b = row >> 11, s = row & (S - 1);
          obf[(((size_t)b * H + h) * S + s) * D + d] = f2bf(v * 0.125f);
        } else if (MODE == 1) {
          const int h = col >> 6, d = col & 63, b = row >> 11, s = row & (S - 1);
          obf[(((size_t)b * H + h) * S + s) * D + d] = f2bf(v);
        } else if (MODE == 2) {
          const int h = col >> 6, d = col & 63, b = row >> 11, s = row & (S - 1);
          obf[(((size_t)b * H + h) * D + d) * S + s] = f2bf(v);
        } else {
          of32[(size_t)row * E + col] = v;
        }
      }
    }
  }
}

// ---------------- flash attention (LDS-staged K/V, swapped-operand) -------
// grid: (S/64, B*H), 4 waves/block, each wave owns 16 q-rows of the block's
// 64. K/V tiles [64 x 64] staged in LDS once per block (double-buffered,
// global_load_lds, both-sides granule swizzle), shared by all 4 waves.
// Swapped MFMA: QK^T = mfma(K,Q) -> lane owns one q-row, 16 scores in-reg.
// PV = mfma(V^T, P^T). Qh pre-scaled by 1/sqrt(D). Vt is [B][H][D][S].
// XCD swizzle packs 4 heads per XCD so staged K/V reads are L2-resident.
__global__ __launch_bounds__(256) void attn_kernel(
    const unsigned short* __restrict__ Qh, const unsigned short* __restrict__ Kh,
    const unsigned short* __restrict__ Vt, unsigned short* __restrict__ Xb) {
  __shared__ __align__(16) unsigned short Ks[2][64 * 64];
  __shared__ __align__(16) unsigned short Vs[2][64 * 64];
  __shared__ __align__(16) unsigned short Plds[4][16 * 72];  // row pad 64->72

  const int wave = threadIdx.x >> 6;
  const int lane = threadIdx.x & 63;
  const int lr = lane & 15;       // q index within 16
  const int jj = lane >> 4;       // fragment k-group (0..3)
  const int lk = jj * 8;

  // XCD-aware swizzle (1024 blocks, 1024%8==0 -> bijective):
  // consecutive-launch blocks round-robin XCDs; give XCD k a contiguous
  // chunk of 128 remapped blocks = 4 heads -> 4*512KB = 2MB K/V in its L2.
  const int lin = blockIdx.x + (blockIdx.y << 5);  // gridDim.x == 32
  const int nlin = (lin & 7) * 128 + (lin >> 3);
  const int qt = nlin & 31;
  const int bh = nlin >> 5;
  const int q0 = qt * 64 + wave * 16;

  const unsigned short* Qp = Qh + ((size_t)bh * S + q0) * D;
  short8 qf0 = *reinterpret_cast<const short8*>(Qp + (size_t)lr * D + lk);
  short8 qf1 = *reinterpret_cast<const short8*>(Qp + (size_t)lr * D + 32 + lk);

  const unsigned short* Kbase = Kh + (size_t)bh * S * D;
  const unsigned short* Vbase = Vt + (size_t)bh * D * S;

  const f32x4 fz = {0.f, 0.f, 0.f, 0.f};
  float mrun = -3.0e38f, lsum = 0.f;
  f32x4 acc[4];
#pragma unroll
  for (int dt = 0; dt < 4; ++dt) acc[dt] = fz;

  unsigned short* Pw = &Plds[wave][0];

  // staging geometry: 8 chunks of 1KB per tile (8 rows x 128B each);
  // granule swizzle g = (l&7)^(l>>3) so LDS row r holds granule (g^(r&7))
  // at slot g -> b128 row-reads are 2-way bank-conflict (free).
  const int srow = lane >> 3;           // row within chunk (0..7)
  const int sg = (lane & 7) ^ srow;     // swizzled source granule

#define STAGE_KV(buf, kt)                                                     \
  {                                                                           \
    _Pragma("unroll") for (int i = 0; i < 2; ++i) {                           \
      const int c = wave * 2 + i;                                             \
      gload_lds16(Kbase + (size_t)((kt) + c * 8 + srow) * D + sg * 8,         \
                  &Ks[buf][c * 512]);                                         \
      gload_lds16(Vbase + (size_t)(c * 8 + srow) * S + (kt) + sg * 8,         \
                  &Vs[buf][c * 512]);                                         \
    }                                                                         \
  }

  STAGE_KV(0, 0);
  __syncthreads();  // prologue drain: tile 0 ready
  int buf = 0;

  constexpr int NT = S / 64;
  for (int t = 0; t < NT; ++t) {
    if (t + 1 < NT) STAGE_KV(buf ^ 1, (t + 1) * 64);  // prefetch next tile

    // QK^T from LDS K (swizzled read)
    f32x4 sf[4];
    __builtin_amdgcn_s_setprio(1);
#pragma unroll
    for (int nt = 0; nt < 4; ++nt) {
      const int r = nt * 16 + lr;
      const int rx = r & 7;
      short8 kf0 = *reinterpret_cast<const short8*>(
          &Ks[buf][r * 64 + ((jj ^ rx) * 8)]);
      short8 kf1 = *reinterpret_cast<const short8*>(
          &Ks[buf][r * 64 + (((jj + 4) ^ rx) * 8)]);
      f32x4 z = fz;
      z = MFMA16(kf0, qf0, z);   // swapped: col=q, row=key
      z = MFMA16(kf1, qf1, z);
      sf[nt] = z;                // sf[nt][r]: key = nt*16 + 4*jj + r, q = lr
    }
    __builtin_amdgcn_s_setprio(0);

    // V fragments from LDS (issued early; latency hides under softmax)
    short8 vf0[4], vf1[4];
#pragma unroll
    for (int dt = 0; dt < 4; ++dt) {
      const int r = dt * 16 + lr;
      const int rx = r & 7;
      vf0[dt] = *reinterpret_cast<const short8*>(
          &Vs[buf][r * 64 + ((jj ^ rx) * 8)]);
      vf1[dt] = *reinterpret_cast<const short8*>(
          &Vs[buf][r * 64 + (((jj + 4) ^ rx) * 8)]);
    }

    // in-lane softmax for q=lr over this lane's 16 keys, then 2-shfl combine
    float mx = sf[0][0];
#pragma unroll
    for (int nt = 0; nt < 4; ++nt)
#pragma unroll
      for (int r = 0; r < 4; ++r) mx = fmaxf(mx, sf[nt][r]);
    mx = fmaxf(mx, __shfl_xor(mx, 16));
    mx = fmaxf(mx, __shfl_xor(mx, 32));
    const float nm = fmaxf(mrun, mx);
    const float fac = __expf(mrun - nm);
    mrun = nm;
    float p[4][4];
    float rs = 0.f;
#pragma unroll
    for (int nt = 0; nt < 4; ++nt)
#pragma unroll
      for (int r = 0; r < 4; ++r) {
        p[nt][r] = __expf(sf[nt][r] - nm);
        rs += p[nt][r];
      }
    rs += __shfl_xor(rs, 16);
    rs += __shfl_xor(rs, 32);
    lsum = lsum * fac + rs;
#pragma unroll
    for (int dt = 0; dt < 4; ++dt)
#pragma unroll
      for (int r = 0; r < 4; ++r) acc[dt][r] *= fac;

    // P^T re-layout: lane holds 4 consecutive keys per nt -> packed b64
    // writes into row-padded [16][72] (2-way banks, free).
#pragma unroll
    for (int nt = 0; nt < 4; ++nt) {
      us4 w;
      w.x = f2bf(p[nt][0]); w.y = f2bf(p[nt][1]);
      w.z = f2bf(p[nt][2]); w.w = f2bf(p[nt][3]);
      *reinterpret_cast<us4*>(&Pw[lr * 72 + nt * 16 + 4 * jj]) = w;
    }
    // wave-local ordering: DS pipe is in-order per wave; fence the compiler
    __builtin_amdgcn_sched_barrier(0);
    asm volatile("s_waitcnt lgkmcnt(0)" ::: "memory");
    __builtin_amdgcn_sched_barrier(0);
    short8 pa0 = *reinterpret_cast<const short8*>(&Pw[lr * 72 + 8 * jj]);
    short8 pa1 = *reinterpret_cast<const short8*>(&Pw[lr * 72 + 32 + 8 * jj]);
    __builtin_amdgcn_wave_barrier();  // keep reads ahead of next-iter writes

    __builtin_amdgcn_s_setprio(1);
#pragma unroll
    for (int dt = 0; dt < 4; ++dt) {
      acc[dt] = MFMA16(vf0[dt], pa0, acc[dt]);  // swapped: col=q, row=d
      acc[dt] = MFMA16(vf1[dt], pa1, acc[dt]);
    }
    __builtin_amdgcn_s_setprio(0);

    __syncthreads();  // next tile staged (vmcnt drained) + reads done
    buf ^= 1;
  }
#undef STAGE_KV

  // epilogue: normalize and store (packed us4: 4 consecutive d per lane)
  const float inv = 1.0f / lsum;
  const int b = bh >> 4, h = bh & (H - 1);
  const int row = q0 + lr;
#pragma unroll
  for (int dt = 0; dt < 4; ++dt) {
    us4 o;
#pragma unroll
    for (int r = 0; r < 4; ++r) o[r] = f2bf(acc[dt][r] * inv);
    *reinterpret_cast<us4*>(
        &Xb[((size_t)b * S + row) * E + h * D + dt * 16 + 4 * jj]) = o;
  }
}

extern "C" void kernel_launch(void* const* d_in, const int* in_sizes, int n_in,
                              void* d_out, int out_size, void* d_ws, size_t ws_size,
                              hipStream_t stream) {
  const float* q_f = (const float*)d_in[0];
  const float* k_f = (const float*)d_in[1];
  const float* v_f = (const float*)d_in[2];
  const float* wq_f = (const float*)d_in[3];
  const float* wk_f = (const float*)d_in[4];
  const float* wv_f = (const float*)d_in[5];
  const float* wo_f = (const float*)d_in[6];

  // workspace layout (bf16 halves): 7*NE + 4*NW elements = 64 MB
  unsigned short* xq = (unsigned short*)d_ws;
  unsigned short* xk = xq + NE;
  unsigned short* xv = xk + NE;
  unsigned short* wq = xv + NE;
  unsigned short* wk = wq + NW;
  unsigned short* wv = wk + NW;
  unsigned short* wo = wv + NW;
  unsigned short* Qh = wo + NW;
  unsigned short* Kh = Qh + NE;
  unsigned short* Vt = Kh + NE;
  unsigned short* Xb = Vt + NE;

  // 1) convert inputs + weights to bf16 (2 fused launches)
  cvt_act_kernel<<<dim3(512, 3), 256, 0, stream>>>(q_f, k_f, v_f, xq, xk, xv,
                                                   (int)(NE / 4));
  cvt_w_kernel<<<dim3(256, 4), 256, 0, stream>>>(wq_f, wk_f, wv_f, wo_f, wq, wk,
                                                 wv, wo, (int)(NW / 4));

  // 2) Q/K/V projections
  gemm128_kernel<0><<<dim3(M / 128, E / 128), 256, 0, stream>>>(xq, wq, Qh, nullptr);
  gemm128_kernel<1><<<dim3(M / 128, E / 128), 256, 0, stream>>>(xk, wk, Kh, nullptr);
  gemm128_kernel<2><<<dim3(M / 128, E / 128), 256, 0, stream>>>(xv, wv, Vt, nullptr);

  // 3) flash attention (LDS-staged K/V, 64-row q-tiles)
  attn_kernel<<<dim3(S / 64, B * H), 256, 0, stream>>>(Qh, Kh, Vt, Xb);

  // 4) output projection (fp32 out)
  gemm128_kernel<3><<<dim3(M / 128, E / 128), 256, 0, stream>>>(Xb, wo, nullptr,
                                                                (float*)d_out);
}

// Round 6
// 184.239 us; speedup vs baseline: 1.8392x; 1.0617x over previous
//
#include <hip/hip_runtime.h>
#include <hip/hip_bf16.h>

// MHA: out = softmax((x@Wq^T)(x@Wk^T)^T / sqrt(D)) (x@Wv^T) @ Wo^T
// B=2, S=2048, E=1024, H=16, D=64.

typedef __attribute__((ext_vector_type(8))) short short8;
typedef __attribute__((ext_vector_type(4))) float f32x4;
typedef __attribute__((ext_vector_type(4))) unsigned short us4;
typedef __attribute__((ext_vector_type(4))) int i32x4;

#define MFMA16(a, b, c) __builtin_amdgcn_mfma_f32_16x16x32_bf16(a, b, c, 0, 0, 0)

static constexpr int B = 2;
static constexpr int S = 2048;
static constexpr int E = 1024;
static constexpr int H = 16;
static constexpr int D = 64;
static constexpr int M = B * S;               // 4096 rows in projection GEMMs
static constexpr size_t NE = (size_t)M * E;   // activation elements
static constexpr size_t NW = (size_t)E * E;   // weight elements

// round-to-nearest-even fp32 -> bf16 (bit pattern as ushort)
static __device__ __forceinline__ unsigned short f2bf(float x) {
  unsigned int u = __float_as_uint(x);
  unsigned int r = (u + 0x7FFFu + ((u >> 16) & 1u)) >> 16;
  return (unsigned short)r;
}

// packed fp32x2 -> bf16x2 (RNE), single HW instruction; lo in low 16 bits
static __device__ __forceinline__ int cvt_pk_bf16(float lo, float hi) {
  int r;
  asm("v_cvt_pk_bf16_f32 %0, %1, %2" : "=v"(r) : "v"(lo), "v"(hi));
  return r;
}

// async global -> LDS, 16B per lane. LDS dest = wave-uniform base + lane*16.
static __device__ __forceinline__ void gload_lds16(const unsigned short* g,
                                                   unsigned short* l) {
  __builtin_amdgcn_global_load_lds(
      (const __attribute__((address_space(1))) unsigned int*)g,
      (__attribute__((address_space(3))) unsigned int*)l, 16, 0, 0);
}

// ---------------- fp32 -> bf16 conversion (fused, z-indexed) --------------
__global__ void cvt_act_kernel(const float* __restrict__ s0,
                               const float* __restrict__ s1,
                               const float* __restrict__ s2,
                               unsigned short* __restrict__ d0,
                               unsigned short* __restrict__ d1,
                               unsigned short* __restrict__ d2, int n4) {
  const float* src = (blockIdx.y == 0) ? s0 : ((blockIdx.y == 1) ? s1 : s2);
  unsigned short* dst = (blockIdx.y == 0) ? d0 : ((blockIdx.y == 1) ? d1 : d2);
  for (int i = blockIdx.x * blockDim.x + threadIdx.x; i < n4;
       i += gridDim.x * blockDim.x) {
    float4 v = reinterpret_cast<const float4*>(src)[i];
    ushort4 o;
    o.x = f2bf(v.x); o.y = f2bf(v.y); o.z = f2bf(v.z); o.w = f2bf(v.w);
    reinterpret_cast<ushort4*>(dst)[i] = o;
  }
}

__global__ void cvt_w_kernel(const float* __restrict__ s0,
                             const float* __restrict__ s1,
                             const float* __restrict__ s2,
                             const float* __restrict__ s3,
                             unsigned short* __restrict__ d0,
                             unsigned short* __restrict__ d1,
                             unsigned short* __restrict__ d2,
                             unsigned short* __restrict__ d3, int n4) {
  const int z = blockIdx.y;
  const float* src = (z == 0) ? s0 : ((z == 1) ? s1 : ((z == 2) ? s2 : s3));
  unsigned short* dst = (z == 0) ? d0 : ((z == 1) ? d1 : ((z == 2) ? d2 : d3));
  for (int i = blockIdx.x * blockDim.x + threadIdx.x; i < n4;
       i += gridDim.x * blockDim.x) {
    float4 v = reinterpret_cast<const float4*>(src)[i];
    ushort4 o;
    o.x = f2bf(v.x); o.y = f2bf(v.y); o.z = f2bf(v.z); o.w = f2bf(v.w);
    reinterpret_cast<ushort4*>(dst)[i] = o;
  }
}

// ---------------- 128x128-tile GEMM: out = A @ W^T (m97 structure) --------
// A: [M][E] bf16. W: [N=E][E] bf16 (row = out col). BK=32, 4 waves 2x2,
// global_load_lds width-16 staging, 2 barriers per K-step.
// MODE 0: Q -> Qh[B][H][S][D] * 0.125*log2(e)  (exp2-domain softmax)
// MODE 1: K -> Kh[B][H][S][D]
// MODE 2: V -> Vt[B][H][D][S]           MODE 3: fp32 row-major out
template <int MODE>
__global__ __launch_bounds__(256) void gemm128_kernel(
    const unsigned short* __restrict__ A, const unsigned short* __restrict__ W,
    unsigned short* __restrict__ obf, float* __restrict__ of32) {
  __shared__ __align__(16) unsigned short As[128 * 32];
  __shared__ __align__(16) unsigned short Bs[128 * 32];

  const int wave = threadIdx.x >> 6;
  const int lane = threadIdx.x & 63;
  const int lr = lane & 15;
  const int lk = (lane >> 4) * 8;
  const int m0 = blockIdx.x * 128;
  const int n0 = blockIdx.y * 128;
  const int wm = (wave >> 1) * 64;
  const int wn = (wave & 1) * 64;
  const int srow = lane >> 2;        // row within 16-row staging chunk
  const int scol = (lane & 3) * 8;   // element col within BK=32

  f32x4 acc[4][4];
  const f32x4 fz = {0.f, 0.f, 0.f, 0.f};
#pragma unroll
  for (int i = 0; i < 4; ++i)
#pragma unroll
    for (int j = 0; j < 4; ++j) acc[i][j] = fz;

  for (int kk = 0; kk < E; kk += 32) {
    // stage A[128][32], B[128][32]; chunk c = 16 rows = 1KB = one wave issue
#pragma unroll
    for (int i = 0; i < 2; ++i) {
      const int c = wave * 2 + i;
      const int row = c * 16 + srow;
      gload_lds16(A + (size_t)(m0 + row) * E + kk + scol, &As[c * 512]);
      gload_lds16(W + (size_t)(n0 + row) * E + kk + scol, &Bs[c * 512]);
    }
    __syncthreads();  // drains vmcnt(0): LDS tiles ready
    short8 af[4], bw[4];
#pragma unroll
    for (int i = 0; i < 4; ++i)
      af[i] = *reinterpret_cast<const short8*>(&As[(wm + i * 16 + lr) * 32 + lk]);
#pragma unroll
    for (int j = 0; j < 4; ++j)
      bw[j] = *reinterpret_cast<const short8*>(&Bs[(wn + j * 16 + lr) * 32 + lk]);
#pragma unroll
    for (int i = 0; i < 4; ++i)
#pragma unroll
      for (int j = 0; j < 4; ++j) acc[i][j] = MFMA16(af[i], bw[j], acc[i][j]);
    __syncthreads();  // reads done before next stage overwrites
  }

  const int rbase = (lane >> 4) * 4;
#pragma unroll
  for (int i = 0; i < 4; ++i) {
#pragma unroll
    for (int j = 0; j < 4; ++j) {
      const int col = n0 + wn + j * 16 + lr;
#pragma unroll
      for (int r = 0; r < 4; ++r) {
        const int row = m0 + wm + i * 16 + rbase + r;
        const float v = acc[i][j][r];
        if (MODE == 0) {
          const int h = col >> 6, d = col & 63, b = row >> 11, s = row & (S - 1);
          // 0.125 * log2(e): QK scores land in log2 domain for native v_exp
          obf[(((size_t)b * H + h) * S + s) * D + d] = f2bf(v * 0.18033688f);
        } else if (MODE == 1) {
          const int h = col >> 6, d = col & 63, b = row >> 11, s = row & (S - 1);
          obf[(((size_t)b * H + h) * S + s) * D + d] = f2bf(v);
        } else if (MODE == 2) {
          const int h = col >> 6, d = col & 63, b = row >> 11, s = row & (S - 1);
          obf[(((size_t)b * H + h) * D + d) * S + s] = f2bf(v);
        } else {
          of32[(size_t)row * E + col] = v;
        }
      }
    }
  }
}

// ---------------- flash attention (LDS-staged K/V, all-register P) --------
// grid: (S/64, B*H), 4 waves/block, each wave owns 16 q-rows of the block's
// 64. K/V tiles [64 x 64] staged in LDS once per block (double-buffered,
// global_load_lds, both-sides granule swizzle), shared by all 4 waves.
// Swapped QK^T = mfma(K,Q) with PERMUTED key rows per chunk nt:
//   key(nt, m) = 8*(m>>2) + (m&3) + 4*(nt&1) + 32*(nt>>1)   (m = A-row)
// so lane (lr,jj) ends QK holding exactly keys 8jj..8jj+7 (nt=0,1) and
// 32+8jj..+7 (nt=2,3) for q=lr — precisely its PV B-fragment -> P never
// leaves the lane (cvt_pk straight into MFMA operand, no LDS/shfl).
// Softmax in exp2 domain (Q pre-scaled by 0.125*log2e), defer-max THR=8.
// PV = mfma(V^T, P^T). Vt is [B][H][D][S].
__global__ __launch_bounds__(256) void attn_kernel(
    const unsigned short* __restrict__ Qh, const unsigned short* __restrict__ Kh,
    const unsigned short* __restrict__ Vt, unsigned short* __restrict__ Xb) {
  __shared__ __align__(16) unsigned short Ks[2][64 * 64];
  __shared__ __align__(16) unsigned short Vs[2][64 * 64];

  const int wave = threadIdx.x >> 6;
  const int lane = threadIdx.x & 63;
  const int lr = lane & 15;       // q index within 16
  const int jj = lane >> 4;       // fragment k-group (0..3)
  const int lk = jj * 8;

  // XCD-aware swizzle (1024 blocks, 1024%8==0 -> bijective):
  // 128 consecutive remapped blocks = 4 heads per XCD -> 2MB K/V in its L2.
  const int lin = blockIdx.x + (blockIdx.y << 5);  // gridDim.x == 32
  const int nlin = (lin & 7) * 128 + (lin >> 3);
  const int qt = nlin & 31;
  const int bh = nlin >> 5;
  const int q0 = qt * 64 + wave * 16;

  const unsigned short* Qp = Qh + ((size_t)bh * S + q0) * D;
  short8 qf0 = *reinterpret_cast<const short8*>(Qp + (size_t)lr * D + lk);
  short8 qf1 = *reinterpret_cast<const short8*>(Qp + (size_t)lr * D + 32 + lk);

  const unsigned short* Kbase = Kh + (size_t)bh * S * D;
  const unsigned short* Vbase = Vt + (size_t)bh * D * S;

  const f32x4 fz = {0.f, 0.f, 0.f, 0.f};
  float mrun = -3.0e38f, lsum = 0.f;  // lsum: per-lane partial (own 16 keys)
  f32x4 acc[4];
#pragma unroll
  for (int dt = 0; dt < 4; ++dt) acc[dt] = fz;

  // staging geometry: 8 chunks of 1KB per tile (8 rows x 128B each);
  // granule swizzle g = (l&7)^(l>>3): LDS row r holds granule (g^(r&7)) at
  // slot g -> b128 row-reads are 2-way bank-conflict (free).
  const int srow = lane >> 3;           // row within chunk (0..7)
  const int sg = (lane & 7) ^ srow;     // swizzled source granule

#define STAGE_KV(buf, kt)                                                     \
  {                                                                           \
    _Pragma("unroll") for (int i = 0; i < 2; ++i) {                           \
      const int c = wave * 2 + i;                                             \
      gload_lds16(Kbase + (size_t)((kt) + c * 8 + srow) * D + sg * 8,         \
                  &Ks[buf][c * 512]);                                         \
      gload_lds16(Vbase + (size_t)(c * 8 + srow) * S + (kt) + sg * 8,         \
                  &Vs[buf][c * 512]);                                         \
    }                                                                         \
  }

  STAGE_KV(0, 0);
  __syncthreads();  // prologue drain: tile 0 ready
  int buf = 0;

  const int rb = ((lr >> 2) << 3) + (lr & 3);  // permuted A-row base

  constexpr int NT = S / 64;
  for (int t = 0; t < NT; ++t) {
    if (t + 1 < NT) STAGE_KV(buf ^ 1, (t + 1) * 64);  // prefetch next tile

    // QK^T from LDS K (swizzled read, permuted key rows)
    f32x4 sf[4];
    __builtin_amdgcn_s_setprio(1);
#pragma unroll
    for (int nt = 0; nt < 4; ++nt) {
      const int r = rb + ((nt & 1) << 2) + ((nt >> 1) << 5);
      const int rx = r & 7;
      short8 kf0 = *reinterpret_cast<const short8*>(
          &Ks[buf][r * 64 + ((jj ^ rx) * 8)]);
      short8 kf1 = *reinterpret_cast<const short8*>(
          &Ks[buf][r * 64 + (((jj + 4) ^ rx) * 8)]);
      f32x4 z = fz;
      z = MFMA16(kf0, qf0, z);   // swapped: col=q, row=permuted key
      z = MFMA16(kf1, qf1, z);
      sf[nt] = z;  // sf[nt][r_]: key = 8jj + 4*(nt&1) + 32*(nt>>1) + r_, q=lr
    }
    __builtin_amdgcn_s_setprio(0);

    // V fragments from LDS (issued early; latency hides under softmax)
    short8 vf0[4], vf1[4];
#pragma unroll
    for (int dt = 0; dt < 4; ++dt) {
      const int r = dt * 16 + lr;
      const int rx = r & 7;
      vf0[dt] = *reinterpret_cast<const short8*>(
          &Vs[buf][r * 64 + ((jj ^ rx) * 8)]);
      vf1[dt] = *reinterpret_cast<const short8*>(
          &Vs[buf][r * 64 + (((jj + 4) ^ rx) * 8)]);
    }

    // row max across this lane's 16 keys, then 2-shfl across the q-row
    // (lanes lr, lr+16, lr+32, lr+48 hold disjoint key sets of row lr)
    float mx = sf[0][0];
#pragma unroll
    for (int nt = 0; nt < 4; ++nt)
#pragma unroll
      for (int r = 0; r < 4; ++r) mx = fmaxf(mx, sf[nt][r]);
    mx = fmaxf(mx, __shfl_xor(mx, 16));
    mx = fmaxf(mx, __shfl_xor(mx, 32));

    // defer-max: rescale only if the running max grew by > 8 (log2 units);
    // otherwise P is bounded by 2^8 which f32/bf16 tolerate.
    if (__any(mx > mrun + 8.f)) {
      const float nm = fmaxf(mrun, mx);
      const float fac = __builtin_amdgcn_exp2f(mrun - nm);
      mrun = nm;
      lsum *= fac;
#pragma unroll
      for (int dt = 0; dt < 4; ++dt)
#pragma unroll
        for (int r = 0; r < 4; ++r) acc[dt][r] *= fac;
    }

    // p = 2^(s - m); per-lane partial sum; pack in-place for PV B-operand
    float p[4][4];
#pragma unroll
    for (int nt = 0; nt < 4; ++nt)
#pragma unroll
      for (int r = 0; r < 4; ++r) {
        p[nt][r] = __builtin_amdgcn_exp2f(sf[nt][r] - mrun);
        lsum += p[nt][r];
      }
    i32x4 w0, w1;
    w0.x = cvt_pk_bf16(p[0][0], p[0][1]);  // keys 8jj+0,1
    w0.y = cvt_pk_bf16(p[0][2], p[0][3]);  // keys 8jj+2,3
    w0.z = cvt_pk_bf16(p[1][0], p[1][1]);  // keys 8jj+4,5
    w0.w = cvt_pk_bf16(p[1][2], p[1][3]);  // keys 8jj+6,7
    w1.x = cvt_pk_bf16(p[2][0], p[2][1]);  // keys 32+8jj+0,1
    w1.y = cvt_pk_bf16(p[2][2], p[2][3]);
    w1.z = cvt_pk_bf16(p[3][0], p[3][1]);
    w1.w = cvt_pk_bf16(p[3][2], p[3][3]);
    short8 pa0 = __builtin_bit_cast(short8, w0);
    short8 pa1 = __builtin_bit_cast(short8, w1);

    __builtin_amdgcn_s_setprio(1);
#pragma unroll
    for (int dt = 0; dt < 4; ++dt) {
      acc[dt] = MFMA16(vf0[dt], pa0, acc[dt]);  // swapped: col=q, row=d
      acc[dt] = MFMA16(vf1[dt], pa1, acc[dt]);
    }
    __builtin_amdgcn_s_setprio(0);

    __syncthreads();  // next tile staged (vmcnt drained) + reads done
    buf ^= 1;
  }
#undef STAGE_KV

  // combine per-lane partial sums across the q-row, normalize, store
  float ltot = lsum;
  ltot += __shfl_xor(ltot, 16);
  ltot += __shfl_xor(ltot, 32);
  const float inv = 1.0f / ltot;
  const int b = bh >> 4, h = bh & (H - 1);
  const int row = q0 + lr;
#pragma unroll
  for (int dt = 0; dt < 4; ++dt) {
    us4 o;
#pragma unroll
    for (int r = 0; r < 4; ++r) o[r] = f2bf(acc[dt][r] * inv);
    *reinterpret_cast<us4*>(
        &Xb[((size_t)b * S + row) * E + h * D + dt * 16 + 4 * jj]) = o;
  }
}

extern "C" void kernel_launch(void* const* d_in, const int* in_sizes, int n_in,
                              void* d_out, int out_size, void* d_ws, size_t ws_size,
                              hipStream_t stream) {
  const float* q_f = (const float*)d_in[0];
  const float* k_f = (const float*)d_in[1];
  const float* v_f = (const float*)d_in[2];
  const float* wq_f = (const float*)d_in[3];
  const float* wk_f = (const float*)d_in[4];
  const float* wv_f = (const float*)d_in[5];
  const float* wo_f = (const float*)d_in[6];

  // workspace layout (bf16 halves): 7*NE + 4*NW elements = 64 MB
  unsigned short* xq = (unsigned short*)d_ws;
  unsigned short* xk = xq + NE;
  unsigned short* xv = xk + NE;
  unsigned short* wq = xv + NE;
  unsigned short* wk = wq + NW;
  unsigned short* wv = wk + NW;
  unsigned short* wo = wv + NW;
  unsigned short* Qh = wo + NW;
  unsigned short* Kh = Qh + NE;
  unsigned short* Vt = Kh + NE;
  unsigned short* Xb = Vt + NE;

  // 1) convert inputs + weights to bf16 (2 fused launches)
  cvt_act_kernel<<<dim3(512, 3), 256, 0, stream>>>(q_f, k_f, v_f, xq, xk, xv,
                                                   (int)(NE / 4));
  cvt_w_kernel<<<dim3(256, 4), 256, 0, stream>>>(wq_f, wk_f, wv_f, wo_f, wq, wk,
                                                 wv, wo, (int)(NW / 4));

  // 2) Q/K/V projections
  gemm128_kernel<0><<<dim3(M / 128, E / 128), 256, 0, stream>>>(xq, wq, Qh, nullptr);
  gemm128_kernel<1><<<dim3(M / 128, E / 128), 256, 0, stream>>>(xk, wk, Kh, nullptr);
  gemm128_kernel<2><<<dim3(M / 128, E / 128), 256, 0, stream>>>(xv, wv, Vt, nullptr);

  // 3) flash attention (LDS-staged K/V, 64-row q-tiles, register-only P)
  attn_kernel<<<dim3(S / 64, B * H), 256, 0, stream>>>(Qh, Kh, Vt, Xb);

  // 4) output projection (fp32 out)
  gemm128_kernel<3><<<dim3(M / 128, E / 128), 256, 0, stream>>>(Xb, wo, nullptr,
                                                                (float*)d_out);
}

// Round 7
// 159.453 us; speedup vs baseline: 2.1251x; 1.1554x over previous
//
#include <hip/hip_runtime.h>
#include <hip/hip_bf16.h>

// MHA: out = softmax((x@Wq^T)(x@Wk^T)^T / sqrt(D)) (x@Wv^T) @ Wo^T
// B=2, S=2048, E=1024, H=16, D=64.

typedef __attribute__((ext_vector_type(8))) short short8;
typedef __attribute__((ext_vector_type(4))) float f32x4;
typedef __attribute__((ext_vector_type(4))) unsigned short us4;
typedef __attribute__((ext_vector_type(4))) int i32x4;

#define MFMA16(a, b, c) __builtin_amdgcn_mfma_f32_16x16x32_bf16(a, b, c, 0, 0, 0)

static constexpr int B = 2;
static constexpr int S = 2048;
static constexpr int E = 1024;
static constexpr int H = 16;
static constexpr int D = 64;
static constexpr int M = B * S;               // 4096 rows in projection GEMMs
static constexpr size_t NE = (size_t)M * E;   // activation elements
static constexpr size_t NW = (size_t)E * E;   // weight elements

// round-to-nearest-even fp32 -> bf16 (bit pattern as ushort)
static __device__ __forceinline__ unsigned short f2bf(float x) {
  unsigned int u = __float_as_uint(x);
  unsigned int r = (u + 0x7FFFu + ((u >> 16) & 1u)) >> 16;
  return (unsigned short)r;
}

// packed fp32x2 -> bf16x2 (RNE), single HW instruction; lo in low 16 bits
static __device__ __forceinline__ int cvt_pk_bf16(float lo, float hi) {
  int r;
  asm("v_cvt_pk_bf16_f32 %0, %1, %2" : "=v"(r) : "v"(lo), "v"(hi));
  return r;
}

// async global -> LDS, 16B per lane. LDS dest = wave-uniform base + lane*16.
static __device__ __forceinline__ void gload_lds16(const unsigned short* g,
                                                   unsigned short* l) {
  __builtin_amdgcn_global_load_lds(
      (const __attribute__((address_space(1))) unsigned int*)g,
      (__attribute__((address_space(3))) unsigned int*)l, 16, 0, 0);
}

// ---------------- fp32 -> bf16 conversion (fused, z-indexed) --------------
__global__ void cvt_act_kernel(const float* __restrict__ s0,
                               const float* __restrict__ s1,
                               const float* __restrict__ s2,
                               unsigned short* __restrict__ d0,
                               unsigned short* __restrict__ d1,
                               unsigned short* __restrict__ d2, int n4) {
  const float* src = (blockIdx.y == 0) ? s0 : ((blockIdx.y == 1) ? s1 : s2);
  unsigned short* dst = (blockIdx.y == 0) ? d0 : ((blockIdx.y == 1) ? d1 : d2);
  for (int i = blockIdx.x * blockDim.x + threadIdx.x; i < n4;
       i += gridDim.x * blockDim.x) {
    float4 v = reinterpret_cast<const float4*>(src)[i];
    ushort4 o;
    o.x = f2bf(v.x); o.y = f2bf(v.y); o.z = f2bf(v.z); o.w = f2bf(v.w);
    reinterpret_cast<ushort4*>(dst)[i] = o;
  }
}

__global__ void cvt_w_kernel(const float* __restrict__ s0,
                             const float* __restrict__ s1,
                             const float* __restrict__ s2,
                             const float* __restrict__ s3,
                             unsigned short* __restrict__ d0,
                             unsigned short* __restrict__ d1,
                             unsigned short* __restrict__ d2,
                             unsigned short* __restrict__ d3, int n4) {
  const int z = blockIdx.y;
  const float* src = (z == 0) ? s0 : ((z == 1) ? s1 : ((z == 2) ? s2 : s3));
  unsigned short* dst = (z == 0) ? d0 : ((z == 1) ? d1 : ((z == 2) ? d2 : d3));
  for (int i = blockIdx.x * blockDim.x + threadIdx.x; i < n4;
       i += gridDim.x * blockDim.x) {
    float4 v = reinterpret_cast<const float4*>(src)[i];
    ushort4 o;
    o.x = f2bf(v.x); o.y = f2bf(v.y); o.z = f2bf(v.z); o.w = f2bf(v.w);
    reinterpret_cast<ushort4*>(dst)[i] = o;
  }
}

// ---------------- fused QKV projection GEMM (double-buffered) -------------
// grid (M/128, E/128, 3). 128x128 tile, BK=32, 4 waves 2x2, global_load_lds
// staging, T3 2-phase: STAGE(next) -> compute(cur) -> one barrier per K-step.
// z==0: Q -> Qh[B][H][S][D] * 0.125*log2(e)   z==1: K -> Kh[B][H][S][D]
// z==2: V -> Vt[B][H][D][S]
__global__ __launch_bounds__(256) void gemm_proj_kernel(
    const unsigned short* __restrict__ xq, const unsigned short* __restrict__ xk,
    const unsigned short* __restrict__ xv, const unsigned short* __restrict__ wq,
    const unsigned short* __restrict__ wk, const unsigned short* __restrict__ wv,
    unsigned short* __restrict__ Qh, unsigned short* __restrict__ Kh,
    unsigned short* __restrict__ Vt) {
  __shared__ __align__(16) unsigned short As[2][128 * 32];
  __shared__ __align__(16) unsigned short Bs[2][128 * 32];

  const int which = blockIdx.z;
  const unsigned short* A = (which == 0) ? xq : ((which == 1) ? xk : xv);
  const unsigned short* W = (which == 0) ? wq : ((which == 1) ? wk : wv);

  const int wave = threadIdx.x >> 6;
  const int lane = threadIdx.x & 63;
  const int lr = lane & 15;
  const int lk = (lane >> 4) * 8;
  const int m0 = blockIdx.x * 128;
  const int n0 = blockIdx.y * 128;
  const int wm = (wave >> 1) * 64;
  const int wn = (wave & 1) * 64;
  const int srow = lane >> 2;        // row within 16-row staging chunk
  const int scol = (lane & 3) * 8;   // element col within BK=32

  f32x4 acc[4][4];
  const f32x4 fz = {0.f, 0.f, 0.f, 0.f};
#pragma unroll
  for (int i = 0; i < 4; ++i)
#pragma unroll
    for (int j = 0; j < 4; ++j) acc[i][j] = fz;

#define STAGE_G(bb, kk)                                                       \
  {                                                                           \
    _Pragma("unroll") for (int i = 0; i < 2; ++i) {                           \
      const int c = wave * 2 + i;                                             \
      const int row = c * 16 + srow;                                          \
      gload_lds16(A + (size_t)(m0 + row) * E + (kk) + scol, &As[bb][c * 512]);\
      gload_lds16(W + (size_t)(n0 + row) * E + (kk) + scol, &Bs[bb][c * 512]);\
    }                                                                         \
  }

  STAGE_G(0, 0);
  __syncthreads();
  int buf = 0;
  for (int kk = 0; kk < E; kk += 32) {
    if (kk + 32 < E) STAGE_G(buf ^ 1, kk + 32);  // prefetch next K-tile
    short8 af[4], bw[4];
#pragma unroll
    for (int i = 0; i < 4; ++i)
      af[i] = *reinterpret_cast<const short8*>(
          &As[buf][(wm + i * 16 + lr) * 32 + lk]);
#pragma unroll
    for (int j = 0; j < 4; ++j)
      bw[j] = *reinterpret_cast<const short8*>(
          &Bs[buf][(wn + j * 16 + lr) * 32 + lk]);
#pragma unroll
    for (int i = 0; i < 4; ++i)
#pragma unroll
      for (int j = 0; j < 4; ++j) acc[i][j] = MFMA16(af[i], bw[j], acc[i][j]);
    __syncthreads();  // drains vmcnt(0): next tile staged; reads done
    buf ^= 1;
  }
#undef STAGE_G

  const int rbase = (lane >> 4) * 4;
#pragma unroll
  for (int i = 0; i < 4; ++i) {
#pragma unroll
    for (int j = 0; j < 4; ++j) {
      const int col = n0 + wn + j * 16 + lr;
      const int h = col >> 6, d = col & 63;
#pragma unroll
      for (int r = 0; r < 4; ++r) {
        const int row = m0 + wm + i * 16 + rbase + r;
        const int b = row >> 11, s = row & (S - 1);
        const float v = acc[i][j][r];
        if (which == 0) {
          // 0.125 * log2(e): QK scores land in log2 domain for native v_exp
          Qh[(((size_t)b * H + h) * S + s) * D + d] = f2bf(v * 0.18033688f);
        } else if (which == 1) {
          Kh[(((size_t)b * H + h) * S + s) * D + d] = f2bf(v);
        } else {
          Vt[(((size_t)b * H + h) * D + d) * S + s] = f2bf(v);
        }
      }
    }
  }
}

// ---------------- output GEMM: out = X @ Wo^T (128x64 tile, dbuf) ---------
// grid (M/128, E/64) = 512 blocks -> 2 blocks/CU for overlap.
__global__ __launch_bounds__(256) void gemm_out_kernel(
    const unsigned short* __restrict__ X, const unsigned short* __restrict__ Wo,
    float* __restrict__ out) {
  __shared__ __align__(16) unsigned short As[2][128 * 32];
  __shared__ __align__(16) unsigned short Bs[2][64 * 32];

  const int wave = threadIdx.x >> 6;
  const int lane = threadIdx.x & 63;
  const int lr = lane & 15;
  const int lk = (lane >> 4) * 8;
  const int m0 = blockIdx.x * 128;
  const int n0 = blockIdx.y * 64;
  const int wm = (wave >> 1) * 64;
  const int wn = (wave & 1) * 32;
  const int srow = lane >> 2;
  const int scol = (lane & 3) * 8;

  f32x4 acc[4][2];
  const f32x4 fz = {0.f, 0.f, 0.f, 0.f};
#pragma unroll
  for (int i = 0; i < 4; ++i)
#pragma unroll
    for (int j = 0; j < 2; ++j) acc[i][j] = fz;

#define STAGE_O(bb, kk)                                                       \
  {                                                                           \
    _Pragma("unroll") for (int i = 0; i < 2; ++i) {                           \
      const int c = wave * 2 + i;                                             \
      const int row = c * 16 + srow;                                          \
      gload_lds16(X + (size_t)(m0 + row) * E + (kk) + scol, &As[bb][c * 512]);\
    }                                                                         \
    gload_lds16(Wo + (size_t)(n0 + wave * 16 + srow) * E + (kk) + scol,       \
                &Bs[bb][wave * 512]);                                         \
  }

  STAGE_O(0, 0);
  __syncthreads();
  int buf = 0;
  for (int kk = 0; kk < E; kk += 32) {
    if (kk + 32 < E) STAGE_O(buf ^ 1, kk + 32);
    short8 af[4], bw[2];
#pragma unroll
    for (int i = 0; i < 4; ++i)
      af[i] = *reinterpret_cast<const short8*>(
          &As[buf][(wm + i * 16 + lr) * 32 + lk]);
#pragma unroll
    for (int j = 0; j < 2; ++j)
      bw[j] = *reinterpret_cast<const short8*>(
          &Bs[buf][(wn + j * 16 + lr) * 32 + lk]);
#pragma unroll
    for (int i = 0; i < 4; ++i)
#pragma unroll
      for (int j = 0; j < 2; ++j) acc[i][j] = MFMA16(af[i], bw[j], acc[i][j]);
    __syncthreads();
    buf ^= 1;
  }
#undef STAGE_O

  const int rbase = (lane >> 4) * 4;
#pragma unroll
  for (int i = 0; i < 4; ++i) {
#pragma unroll
    for (int j = 0; j < 2; ++j) {
      const int col = n0 + wn + j * 16 + lr;
#pragma unroll
      for (int r = 0; r < 4; ++r) {
        const int row = m0 + wm + i * 16 + rbase + r;
        out[(size_t)row * E + col] = acc[i][j][r];
      }
    }
  }
}

// ---------------- flash attention (LDS-staged K/V, all-register P) --------
// grid: (S/64, B*H), 4 waves/block, each wave owns 16 q-rows of the block's
// 64. K/V tiles [64 x 64] staged in LDS once per block (double-buffered,
// global_load_lds, both-sides granule swizzle), shared by all 4 waves.
// Swizzle functions differ per tile to match read-row bit entropy:
//   K rows r = 8(lr>>2)+(lr&3)+4(nt&1)+32(nt>>1): varying bits {0,1,3}
//     -> swzK(r) = (r&3)|(((r>>3)&1)<<2)
//   V rows r = 16dt+lr: varying bits {0,1,2} -> swzV(r) = r&7
// Swapped QK^T = mfma(K,Q) with PERMUTED key rows so lane (lr,jj) ends
// holding exactly its PV B-fragment keys -> P never leaves the lane.
// Softmax in exp2 domain (Q pre-scaled by 0.125*log2e), defer-max THR=8.
// PV = mfma(V^T, P^T). Vt is [B][H][D][S].
__global__ __launch_bounds__(256) void attn_kernel(
    const unsigned short* __restrict__ Qh, const unsigned short* __restrict__ Kh,
    const unsigned short* __restrict__ Vt, unsigned short* __restrict__ Xb) {
  __shared__ __align__(16) unsigned short Ks[2][64 * 64];
  __shared__ __align__(16) unsigned short Vs[2][64 * 64];

  const int wave = threadIdx.x >> 6;
  const int lane = threadIdx.x & 63;
  const int lr = lane & 15;       // q index within 16
  const int jj = lane >> 4;       // fragment k-group (0..3)
  const int lk = jj * 8;

  // XCD-aware swizzle (1024 blocks, 1024%8==0 -> bijective):
  // 128 consecutive remapped blocks = 4 heads per XCD -> 2MB K/V in its L2.
  const int lin = blockIdx.x + (blockIdx.y << 5);  // gridDim.x == 32
  const int nlin = (lin & 7) * 128 + (lin >> 3);
  const int qt = nlin & 31;
  const int bh = nlin >> 5;
  const int q0 = qt * 64 + wave * 16;

  const unsigned short* Qp = Qh + ((size_t)bh * S + q0) * D;
  short8 qf0 = *reinterpret_cast<const short8*>(Qp + (size_t)lr * D + lk);
  short8 qf1 = *reinterpret_cast<const short8*>(Qp + (size_t)lr * D + 32 + lk);

  const unsigned short* Kbase = Kh + (size_t)bh * S * D;
  const unsigned short* Vbase = Vt + (size_t)bh * D * S;

  const f32x4 fz = {0.f, 0.f, 0.f, 0.f};
  float mrun = -3.0e38f, lsum = 0.f;  // lsum: per-lane partial (own 16 keys)
  f32x4 acc[4];
#pragma unroll
  for (int dt = 0; dt < 4; ++dt) acc[dt] = fz;

  // staging geometry: 8 chunks of 1KB per tile (8 rows x 128B each).
  // LDS[row][slot] holds global granule slot^swz(row); read granule g of
  // row r at slot g^swz(r).
  const int srow = lane >> 3;           // row within chunk (0..7)
  const int sgV = (lane & 7) ^ srow;    // V: swzV(rt) = rt&7 = srow

#define STAGE_KV(bb, kt)                                                      \
  {                                                                           \
    _Pragma("unroll") for (int i = 0; i < 2; ++i) {                           \
      const int c = wave * 2 + i;                                             \
      const int sgK = (lane & 7) ^ ((srow & 3) | ((c & 1) << 2));             \
      gload_lds16(Kbase + (size_t)((kt) + c * 8 + srow) * D + sgK * 8,        \
                  &Ks[bb][c * 512]);                                          \
      gload_lds16(Vbase + (size_t)(c * 8 + srow) * S + (kt) + sgV * 8,        \
                  &Vs[bb][c * 512]);                                          \
    }                                                                         \
  }

  STAGE_KV(0, 0);
  __syncthreads();  // prologue drain: tile 0 ready
  int buf = 0;

  const int rb = ((lr >> 2) << 3) + (lr & 3);  // permuted A-row base
  const int kswz = (lr & 3) | (((lr >> 2) & 1) << 2);  // swzK of all K rows
  const int vswz = lr & 7;                             // swzV of all V rows

  constexpr int NT = S / 64;
  for (int t = 0; t < NT; ++t) {
    if (t + 1 < NT) STAGE_KV(buf ^ 1, (t + 1) * 64);  // prefetch next tile

    // QK^T from LDS K (swizzled read, permuted key rows)
    f32x4 sf[4];
    __builtin_amdgcn_s_setprio(1);
#pragma unroll
    for (int nt = 0; nt < 4; ++nt) {
      const int r = rb + ((nt & 1) << 2) + ((nt >> 1) << 5);
      short8 kf0 = *reinterpret_cast<const short8*>(
          &Ks[buf][r * 64 + ((jj ^ kswz) * 8)]);
      short8 kf1 = *reinterpret_cast<const short8*>(
          &Ks[buf][r * 64 + (((jj + 4) ^ kswz) * 8)]);
      f32x4 z = fz;
      z = MFMA16(kf0, qf0, z);   // swapped: col=q, row=permuted key
      z = MFMA16(kf1, qf1, z);
      sf[nt] = z;  // sf[nt][r_]: key = 8jj + 4*(nt&1) + 32*(nt>>1) + r_, q=lr
    }
    __builtin_amdgcn_s_setprio(0);

    // V fragments from LDS (issued early; latency hides under softmax)
    short8 vf0[4], vf1[4];
#pragma unroll
    for (int dt = 0; dt < 4; ++dt) {
      const int r = dt * 16 + lr;
      vf0[dt] = *reinterpret_cast<const short8*>(
          &Vs[buf][r * 64 + ((jj ^ vswz) * 8)]);
      vf1[dt] = *reinterpret_cast<const short8*>(
          &Vs[buf][r * 64 + (((jj + 4) ^ vswz) * 8)]);
    }

    // row max across this lane's 16 keys, then 2-shfl across the q-row
    float mx = sf[0][0];
#pragma unroll
    for (int nt = 0; nt < 4; ++nt)
#pragma unroll
      for (int r = 0; r < 4; ++r) mx = fmaxf(mx, sf[nt][r]);
    mx = fmaxf(mx, __shfl_xor(mx, 16));
    mx = fmaxf(mx, __shfl_xor(mx, 32));

    // defer-max: rescale only if the running max grew by > 8 (log2 units)
    if (__any(mx > mrun + 8.f)) {
      const float nm = fmaxf(mrun, mx);
      const float fac = __builtin_amdgcn_exp2f(mrun - nm);
      mrun = nm;
      lsum *= fac;
#pragma unroll
      for (int dt = 0; dt < 4; ++dt)
#pragma unroll
        for (int r = 0; r < 4; ++r) acc[dt][r] *= fac;
    }

    // p = 2^(s - m); per-lane partial sum; pack in-place for PV B-operand
    float p[4][4];
#pragma unroll
    for (int nt = 0; nt < 4; ++nt)
#pragma unroll
      for (int r = 0; r < 4; ++r) {
        p[nt][r] = __builtin_amdgcn_exp2f(sf[nt][r] - mrun);
        lsum += p[nt][r];
      }
    i32x4 w0, w1;
    w0.x = cvt_pk_bf16(p[0][0], p[0][1]);  // keys 8jj+0,1
    w0.y = cvt_pk_bf16(p[0][2], p[0][3]);  // keys 8jj+2,3
    w0.z = cvt_pk_bf16(p[1][0], p[1][1]);  // keys 8jj+4,5
    w0.w = cvt_pk_bf16(p[1][2], p[1][3]);  // keys 8jj+6,7
    w1.x = cvt_pk_bf16(p[2][0], p[2][1]);  // keys 32+8jj+0,1
    w1.y = cvt_pk_bf16(p[2][2], p[2][3]);
    w1.z = cvt_pk_bf16(p[3][0], p[3][1]);
    w1.w = cvt_pk_bf16(p[3][2], p[3][3]);
    short8 pa0 = __builtin_bit_cast(short8, w0);
    short8 pa1 = __builtin_bit_cast(short8, w1);

    __builtin_amdgcn_s_setprio(1);
#pragma unroll
    for (int dt = 0; dt < 4; ++dt) {
      acc[dt] = MFMA16(vf0[dt], pa0, acc[dt]);  // swapped: col=q, row=d
      acc[dt] = MFMA16(vf1[dt], pa1, acc[dt]);
    }
    __builtin_amdgcn_s_setprio(0);

    __syncthreads();  // next tile staged (vmcnt drained) + reads done
    buf ^= 1;
  }
#undef STAGE_KV

  // combine per-lane partial sums across the q-row, normalize, store
  float ltot = lsum;
  ltot += __shfl_xor(ltot, 16);
  ltot += __shfl_xor(ltot, 32);
  const float inv = 1.0f / ltot;
  const int b = bh >> 4, h = bh & (H - 1);
  const int row = q0 + lr;
#pragma unroll
  for (int dt = 0; dt < 4; ++dt) {
    us4 o;
#pragma unroll
    for (int r = 0; r < 4; ++r) o[r] = f2bf(acc[dt][r] * inv);
    *reinterpret_cast<us4*>(
        &Xb[((size_t)b * S + row) * E + h * D + dt * 16 + 4 * jj]) = o;
  }
}

extern "C" void kernel_launch(void* const* d_in, const int* in_sizes, int n_in,
                              void* d_out, int out_size, void* d_ws, size_t ws_size,
                              hipStream_t stream) {
  const float* q_f = (const float*)d_in[0];
  const float* k_f = (const float*)d_in[1];
  const float* v_f = (const float*)d_in[2];
  const float* wq_f = (const float*)d_in[3];
  const float* wk_f = (const float*)d_in[4];
  const float* wv_f = (const float*)d_in[5];
  const float* wo_f = (const float*)d_in[6];

  // workspace layout (bf16 halves): 7*NE + 4*NW elements = 64 MB
  unsigned short* xq = (unsigned short*)d_ws;
  unsigned short* xk = xq + NE;
  unsigned short* xv = xk + NE;
  unsigned short* wq = xv + NE;
  unsigned short* wk = wq + NW;
  unsigned short* wv = wk + NW;
  unsigned short* wo = wv + NW;
  unsigned short* Qh = wo + NW;
  unsigned short* Kh = Qh + NE;
  unsigned short* Vt = Kh + NE;
  unsigned short* Xb = Vt + NE;

  // 1) convert inputs + weights to bf16 (2 fused launches)
  cvt_act_kernel<<<dim3(512, 3), 256, 0, stream>>>(q_f, k_f, v_f, xq, xk, xv,
                                                   (int)(NE / 4));
  cvt_w_kernel<<<dim3(256, 4), 256, 0, stream>>>(wq_f, wk_f, wv_f, wo_f, wq, wk,
                                                 wv, wo, (int)(NW / 4));

  // 2) fused Q/K/V projections (768 blocks = 3 blocks/CU)
  gemm_proj_kernel<<<dim3(M / 128, E / 128, 3), 256, 0, stream>>>(
      xq, xk, xv, wq, wk, wv, Qh, Kh, Vt);

  // 3) flash attention (LDS-staged K/V, 64-row q-tiles, register-only P)
  attn_kernel<<<dim3(S / 64, B * H), 256, 0, stream>>>(Qh, Kh, Vt, Xb);

  // 4) output projection (512 blocks = 2 blocks/CU, fp32 out)
  gemm_out_kernel<<<dim3(M / 128, E / 64), 256, 0, stream>>>(Xb, wo,
                                                             (float*)d_out);
}

// Round 8
// 145.368 us; speedup vs baseline: 2.3310x; 1.0969x over previous
//
#include <hip/hip_runtime.h>
#include <hip/hip_bf16.h>

// MHA: out = softmax((x@Wq^T)(x@Wk^T)^T / sqrt(D)) (x@Wv^T) @ Wo^T
// B=2, S=2048, E=1024, H=16, D=64.

typedef __attribute__((ext_vector_type(8))) short short8;
typedef __attribute__((ext_vector_type(4))) float f32x4;
typedef __attribute__((ext_vector_type(4))) unsigned short us4;
typedef __attribute__((ext_vector_type(4))) int i32x4;

#define MFMA16(a, b, c) __builtin_amdgcn_mfma_f32_16x16x32_bf16(a, b, c, 0, 0, 0)

static constexpr int B = 2;
static constexpr int S = 2048;
static constexpr int E = 1024;
static constexpr int H = 16;
static constexpr int D = 64;
static constexpr int M = B * S;               // 4096 rows in projection GEMMs
static constexpr size_t NE = (size_t)M * E;   // activation elements
static constexpr size_t NW = (size_t)E * E;   // weight elements

// round-to-nearest-even fp32 -> bf16 (bit pattern as ushort)
static __device__ __forceinline__ unsigned short f2bf(float x) {
  unsigned int u = __float_as_uint(x);
  unsigned int r = (u + 0x7FFFu + ((u >> 16) & 1u)) >> 16;
  return (unsigned short)r;
}

// packed fp32x2 -> bf16x2 (RNE), single HW instruction; lo in low 16 bits
static __device__ __forceinline__ int cvt_pk_bf16(float lo, float hi) {
  int r;
  asm("v_cvt_pk_bf16_f32 %0, %1, %2" : "=v"(r) : "v"(lo), "v"(hi));
  return r;
}

// async global -> LDS, 16B per lane. LDS dest = wave-uniform base + lane*16.
static __device__ __forceinline__ void gload_lds16(const unsigned short* g,
                                                   unsigned short* l) {
  __builtin_amdgcn_global_load_lds(
      (const __attribute__((address_space(1))) unsigned int*)g,
      (__attribute__((address_space(3))) unsigned int*)l, 16, 0, 0);
}

// ---------------- fp32 -> bf16 conversion (fused, z-indexed) --------------
__global__ void cvt_act_kernel(const float* __restrict__ s0,
                               const float* __restrict__ s1,
                               const float* __restrict__ s2,
                               unsigned short* __restrict__ d0,
                               unsigned short* __restrict__ d1,
                               unsigned short* __restrict__ d2, int n4) {
  const float* src = (blockIdx.y == 0) ? s0 : ((blockIdx.y == 1) ? s1 : s2);
  unsigned short* dst = (blockIdx.y == 0) ? d0 : ((blockIdx.y == 1) ? d1 : d2);
  for (int i = blockIdx.x * blockDim.x + threadIdx.x; i < n4;
       i += gridDim.x * blockDim.x) {
    float4 v = reinterpret_cast<const float4*>(src)[i];
    ushort4 o;
    o.x = f2bf(v.x); o.y = f2bf(v.y); o.z = f2bf(v.z); o.w = f2bf(v.w);
    reinterpret_cast<ushort4*>(dst)[i] = o;
  }
}

__global__ void cvt_w_kernel(const float* __restrict__ s0,
                             const float* __restrict__ s1,
                             const float* __restrict__ s2,
                             const float* __restrict__ s3,
                             unsigned short* __restrict__ d0,
                             unsigned short* __restrict__ d1,
                             unsigned short* __restrict__ d2,
                             unsigned short* __restrict__ d3, int n4) {
  const int z = blockIdx.y;
  const float* src = (z == 0) ? s0 : ((z == 1) ? s1 : ((z == 2) ? s2 : s3));
  unsigned short* dst = (z == 0) ? d0 : ((z == 1) ? d1 : ((z == 2) ? d2 : d3));
  for (int i = blockIdx.x * blockDim.x + threadIdx.x; i < n4;
       i += gridDim.x * blockDim.x) {
    float4 v = reinterpret_cast<const float4*>(src)[i];
    ushort4 o;
    o.x = f2bf(v.x); o.y = f2bf(v.y); o.z = f2bf(v.z); o.w = f2bf(v.w);
    reinterpret_cast<ushort4*>(dst)[i] = o;
  }
}

// ---------------- fused QKV projection GEMM (double-buffered) -------------
// grid (M/128, E/128, 3). 128x128 tile, BK=32, 4 waves 2x2, global_load_lds
// staging, T3 2-phase: STAGE(next) -> compute(cur) -> one barrier per K-step.
// z==0: Q -> Qh[B][H][S][D] * 0.125*log2(e)   z==1: K -> Kh[B][H][S][D]
// z==2: V -> Vt[B][H][D][S]
__global__ __launch_bounds__(256) void gemm_proj_kernel(
    const unsigned short* __restrict__ xq, const unsigned short* __restrict__ xk,
    const unsigned short* __restrict__ xv, const unsigned short* __restrict__ wq,
    const unsigned short* __restrict__ wk, const unsigned short* __restrict__ wv,
    unsigned short* __restrict__ Qh, unsigned short* __restrict__ Kh,
    unsigned short* __restrict__ Vt) {
  __shared__ __align__(16) unsigned short As[2][128 * 32];
  __shared__ __align__(16) unsigned short Bs[2][128 * 32];

  const int which = blockIdx.z;
  const unsigned short* A = (which == 0) ? xq : ((which == 1) ? xk : xv);
  const unsigned short* W = (which == 0) ? wq : ((which == 1) ? wk : wv);

  const int wave = threadIdx.x >> 6;
  const int lane = threadIdx.x & 63;
  const int lr = lane & 15;
  const int lk = (lane >> 4) * 8;
  const int m0 = blockIdx.x * 128;
  const int n0 = blockIdx.y * 128;
  const int wm = (wave >> 1) * 64;
  const int wn = (wave & 1) * 64;
  const int srow = lane >> 2;        // row within 16-row staging chunk
  const int scol = (lane & 3) * 8;   // element col within BK=32

  f32x4 acc[4][4];
  const f32x4 fz = {0.f, 0.f, 0.f, 0.f};
#pragma unroll
  for (int i = 0; i < 4; ++i)
#pragma unroll
    for (int j = 0; j < 4; ++j) acc[i][j] = fz;

#define STAGE_G(bb, kk)                                                       \
  {                                                                           \
    _Pragma("unroll") for (int i = 0; i < 2; ++i) {                           \
      const int c = wave * 2 + i;                                             \
      const int row = c * 16 + srow;                                          \
      gload_lds16(A + (size_t)(m0 + row) * E + (kk) + scol, &As[bb][c * 512]);\
      gload_lds16(W + (size_t)(n0 + row) * E + (kk) + scol, &Bs[bb][c * 512]);\
    }                                                                         \
  }

  STAGE_G(0, 0);
  __syncthreads();
  int buf = 0;
  for (int kk = 0; kk < E; kk += 32) {
    if (kk + 32 < E) STAGE_G(buf ^ 1, kk + 32);  // prefetch next K-tile
    short8 af[4], bw[4];
#pragma unroll
    for (int i = 0; i < 4; ++i)
      af[i] = *reinterpret_cast<const short8*>(
          &As[buf][(wm + i * 16 + lr) * 32 + lk]);
#pragma unroll
    for (int j = 0; j < 4; ++j)
      bw[j] = *reinterpret_cast<const short8*>(
          &Bs[buf][(wn + j * 16 + lr) * 32 + lk]);
#pragma unroll
    for (int i = 0; i < 4; ++i)
#pragma unroll
      for (int j = 0; j < 4; ++j) acc[i][j] = MFMA16(af[i], bw[j], acc[i][j]);
    __syncthreads();  // drains vmcnt(0): next tile staged; reads done
    buf ^= 1;
  }
#undef STAGE_G

  const int rbase = (lane >> 4) * 4;
#pragma unroll
  for (int i = 0; i < 4; ++i) {
#pragma unroll
    for (int j = 0; j < 4; ++j) {
      const int col = n0 + wn + j * 16 + lr;
      const int h = col >> 6, d = col & 63;
#pragma unroll
      for (int r = 0; r < 4; ++r) {
        const int row = m0 + wm + i * 16 + rbase + r;
        const int b = row >> 11, s = row & (S - 1);
        const float v = acc[i][j][r];
        if (which == 0) {
          // 0.125 * log2(e): QK scores land in log2 domain for native v_exp
          Qh[(((size_t)b * H + h) * S + s) * D + d] = f2bf(v * 0.18033688f);
        } else if (which == 1) {
          Kh[(((size_t)b * H + h) * S + s) * D + d] = f2bf(v);
        } else {
          Vt[(((size_t)b * H + h) * D + d) * S + s] = f2bf(v);
        }
      }
    }
  }
}

// ---------------- output GEMM: out = X @ Wo^T (128x64 tile, dbuf) ---------
// grid (M/128, E/64) = 512 blocks -> 2 blocks/CU for overlap.
__global__ __launch_bounds__(256) void gemm_out_kernel(
    const unsigned short* __restrict__ X, const unsigned short* __restrict__ Wo,
    float* __restrict__ out) {
  __shared__ __align__(16) unsigned short As[2][128 * 32];
  __shared__ __align__(16) unsigned short Bs[2][64 * 32];

  const int wave = threadIdx.x >> 6;
  const int lane = threadIdx.x & 63;
  const int lr = lane & 15;
  const int lk = (lane >> 4) * 8;
  const int m0 = blockIdx.x * 128;
  const int n0 = blockIdx.y * 64;
  const int wm = (wave >> 1) * 64;
  const int wn = (wave & 1) * 32;
  const int srow = lane >> 2;
  const int scol = (lane & 3) * 8;

  f32x4 acc[4][2];
  const f32x4 fz = {0.f, 0.f, 0.f, 0.f};
#pragma unroll
  for (int i = 0; i < 4; ++i)
#pragma unroll
    for (int j = 0; j < 2; ++j) acc[i][j] = fz;

#define STAGE_O(bb, kk)                                                       \
  {                                                                           \
    _Pragma("unroll") for (int i = 0; i < 2; ++i) {                           \
      const int c = wave * 2 + i;                                             \
      const int row = c * 16 + srow;                                          \
      gload_lds16(X + (size_t)(m0 + row) * E + (kk) + scol, &As[bb][c * 512]);\
    }                                                                         \
    gload_lds16(Wo + (size_t)(n0 + wave * 16 + srow) * E + (kk) + scol,       \
                &Bs[bb][wave * 512]);                                         \
  }

  STAGE_O(0, 0);
  __syncthreads();
  int buf = 0;
  for (int kk = 0; kk < E; kk += 32) {
    if (kk + 32 < E) STAGE_O(buf ^ 1, kk + 32);
    short8 af[4], bw[2];
#pragma unroll
    for (int i = 0; i < 4; ++i)
      af[i] = *reinterpret_cast<const short8*>(
          &As[buf][(wm + i * 16 + lr) * 32 + lk]);
#pragma unroll
    for (int j = 0; j < 2; ++j)
      bw[j] = *reinterpret_cast<const short8*>(
          &Bs[buf][(wn + j * 16 + lr) * 32 + lk]);
#pragma unroll
    for (int i = 0; i < 4; ++i)
#pragma unroll
      for (int j = 0; j < 2; ++j) acc[i][j] = MFMA16(af[i], bw[j], acc[i][j]);
    __syncthreads();
    buf ^= 1;
  }
#undef STAGE_O

  const int rbase = (lane >> 4) * 4;
#pragma unroll
  for (int i = 0; i < 4; ++i) {
#pragma unroll
    for (int j = 0; j < 2; ++j) {
      const int col = n0 + wn + j * 16 + lr;
#pragma unroll
      for (int r = 0; r < 4; ++r) {
        const int row = m0 + wm + i * 16 + rbase + r;
        out[(size_t)row * E + col] = acc[i][j][r];
      }
    }
  }
}

// ---------------- flash attention (32 q-rows/wave, LDS-read amortized) ----
// grid: (S/128, B*H), 4 waves/block; wave owns 32 q-rows (two 16-row groups
// qh=0,1 sharing each K/V LDS fragment -> 16 ds_reads feed 32 MFMAs/tile,
// halving LDS-pipe pressure vs 16-row waves). K/V tiles [64x64] staged in
// LDS (double-buffered, global_load_lds, both-sides granule swizzle).
// Swizzles match read-row bit entropy: K rows vary bits {0,1,3} ->
// swzK(r)=(r&3)|(((r>>3)&1)<<2); V rows vary {0,1,2} -> swzV(r)=r&7.
// Swapped QK^T = mfma(K,Q) with PERMUTED key rows so lane (lr,jj) ends
// holding exactly its PV B-fragment keys -> P never leaves the lane.
// Softmax in exp2 domain (Q pre-scaled by 0.125*log2e), defer-max THR=8.
// PV = mfma(V^T, P^T). Vt is [B][H][D][S].
__global__ __launch_bounds__(256) void attn_kernel(
    const unsigned short* __restrict__ Qh, const unsigned short* __restrict__ Kh,
    const unsigned short* __restrict__ Vt, unsigned short* __restrict__ Xb) {
  __shared__ __align__(16) unsigned short Ks[2][64 * 64];
  __shared__ __align__(16) unsigned short Vs[2][64 * 64];

  const int wave = threadIdx.x >> 6;
  const int lane = threadIdx.x & 63;
  const int lr = lane & 15;       // q index within 16
  const int jj = lane >> 4;       // fragment k-group (0..3)
  const int lk = jj * 8;

  // XCD-aware swizzle (512 blocks, 512%8==0 -> bijective): 64 consecutive
  // remapped blocks = 4 heads per XCD -> 2MB K/V resident in its L2.
  const int lin = blockIdx.x + (blockIdx.y << 4);  // gridDim.x == 16
  const int nlin = (lin & 7) * 64 + (lin >> 3);
  const int qt = nlin & 15;
  const int bh = nlin >> 4;
  const int q0 = qt * 128 + wave * 32;  // wave rows: q0+lr (qh=0), q0+16+lr

  const unsigned short* Qp0 = Qh + ((size_t)bh * S + q0) * D;
  const unsigned short* Qp1 = Qp0 + (size_t)16 * D;
  short8 qa0 = *reinterpret_cast<const short8*>(Qp0 + (size_t)lr * D + lk);
  short8 qa1 = *reinterpret_cast<const short8*>(Qp0 + (size_t)lr * D + 32 + lk);
  short8 qb0 = *reinterpret_cast<const short8*>(Qp1 + (size_t)lr * D + lk);
  short8 qb1 = *reinterpret_cast<const short8*>(Qp1 + (size_t)lr * D + 32 + lk);

  const unsigned short* Kbase = Kh + (size_t)bh * S * D;
  const unsigned short* Vbase = Vt + (size_t)bh * D * S;

  const f32x4 fz = {0.f, 0.f, 0.f, 0.f};
  float mrunA = -3.0e38f, lsumA = 0.f;
  float mrunB = -3.0e38f, lsumB = 0.f;
  f32x4 accA[4], accB[4];
#pragma unroll
  for (int dt = 0; dt < 4; ++dt) { accA[dt] = fz; accB[dt] = fz; }

  // staging geometry: 8 chunks of 1KB per tile (8 rows x 128B each).
  // LDS[row][slot] holds global granule slot^swz(row); read granule g of
  // row r at slot g^swz(r).
  const int srow = lane >> 3;           // row within chunk (0..7)
  const int sgV = (lane & 7) ^ srow;    // V: swzV(rt) = rt&7 = srow

#define STAGE_KV(bb, kt)                                                      \
  {                                                                           \
    _Pragma("unroll") for (int i = 0; i < 2; ++i) {                           \
      const int c = wave * 2 + i;                                             \
      const int sgK = (lane & 7) ^ ((srow & 3) | ((c & 1) << 2));             \
      gload_lds16(Kbase + (size_t)((kt) + c * 8 + srow) * D + sgK * 8,        \
                  &Ks[bb][c * 512]);                                          \
      gload_lds16(Vbase + (size_t)(c * 8 + srow) * S + (kt) + sgV * 8,        \
                  &Vs[bb][c * 512]);                                          \
    }                                                                         \
  }

  STAGE_KV(0, 0);
  __syncthreads();  // prologue drain: tile 0 ready
  int buf = 0;

  const int rb = ((lr >> 2) << 3) + (lr & 3);  // permuted A-row base
  const int kswz = (lr & 3) | (((lr >> 2) & 1) << 2);  // swzK of all K rows
  const int vswz = lr & 7;                             // swzV of all V rows

  constexpr int NT = S / 64;
  for (int t = 0; t < NT; ++t) {
    if (t + 1 < NT) STAGE_KV(buf ^ 1, (t + 1) * 64);  // prefetch next tile

    // QK^T from LDS K (swizzled read, permuted key rows); kf shared by qh=0,1
    f32x4 sfA[4], sfB[4];
    __builtin_amdgcn_s_setprio(1);
#pragma unroll
    for (int nt = 0; nt < 4; ++nt) {
      const int r = rb + ((nt & 1) << 2) + ((nt >> 1) << 5);
      short8 kf0 = *reinterpret_cast<const short8*>(
          &Ks[buf][r * 64 + ((jj ^ kswz) * 8)]);
      short8 kf1 = *reinterpret_cast<const short8*>(
          &Ks[buf][r * 64 + (((jj + 4) ^ kswz) * 8)]);
      f32x4 za = fz, zb = fz;
      za = MFMA16(kf0, qa0, za);   // swapped: col=q, row=permuted key
      za = MFMA16(kf1, qa1, za);
      zb = MFMA16(kf0, qb0, zb);
      zb = MFMA16(kf1, qb1, zb);
      sfA[nt] = za;  // key = 8jj + 4*(nt&1) + 32*(nt>>1) + r_, q = lr
      sfB[nt] = zb;  // same keys, q = lr + 16
    }
    __builtin_amdgcn_s_setprio(0);

    // V fragments from LDS (issued early; latency hides under softmax)
    short8 vf0[4], vf1[4];
#pragma unroll
    for (int dt = 0; dt < 4; ++dt) {
      const int r = dt * 16 + lr;
      vf0[dt] = *reinterpret_cast<const short8*>(
          &Vs[buf][r * 64 + ((jj ^ vswz) * 8)]);
      vf1[dt] = *reinterpret_cast<const short8*>(
          &Vs[buf][r * 64 + (((jj + 4) ^ vswz) * 8)]);
    }

    // ---- softmax, q-group A ----
    float mxA = sfA[0][0];
#pragma unroll
    for (int nt = 0; nt < 4; ++nt)
#pragma unroll
      for (int r = 0; r < 4; ++r) mxA = fmaxf(mxA, sfA[nt][r]);
    mxA = fmaxf(mxA, __shfl_xor(mxA, 16));
    mxA = fmaxf(mxA, __shfl_xor(mxA, 32));
    if (__any(mxA > mrunA + 8.f)) {
      const float nm = fmaxf(mrunA, mxA);
      const float fac = __builtin_amdgcn_exp2f(mrunA - nm);
      mrunA = nm;
      lsumA *= fac;
#pragma unroll
      for (int dt = 0; dt < 4; ++dt)
#pragma unroll
        for (int r = 0; r < 4; ++r) accA[dt][r] *= fac;
    }
    float pA[4][4];
#pragma unroll
    for (int nt = 0; nt < 4; ++nt)
#pragma unroll
      for (int r = 0; r < 4; ++r) {
        pA[nt][r] = __builtin_amdgcn_exp2f(sfA[nt][r] - mrunA);
        lsumA += pA[nt][r];
      }
    i32x4 wa0, wa1;
    wa0.x = cvt_pk_bf16(pA[0][0], pA[0][1]);
    wa0.y = cvt_pk_bf16(pA[0][2], pA[0][3]);
    wa0.z = cvt_pk_bf16(pA[1][0], pA[1][1]);
    wa0.w = cvt_pk_bf16(pA[1][2], pA[1][3]);
    wa1.x = cvt_pk_bf16(pA[2][0], pA[2][1]);
    wa1.y = cvt_pk_bf16(pA[2][2], pA[2][3]);
    wa1.z = cvt_pk_bf16(pA[3][0], pA[3][1]);
    wa1.w = cvt_pk_bf16(pA[3][2], pA[3][3]);
    short8 paA0 = __builtin_bit_cast(short8, wa0);
    short8 paA1 = __builtin_bit_cast(short8, wa1);

    // ---- softmax, q-group B ----
    float mxB = sfB[0][0];
#pragma unroll
    for (int nt = 0; nt < 4; ++nt)
#pragma unroll
      for (int r = 0; r < 4; ++r) mxB = fmaxf(mxB, sfB[nt][r]);
    mxB = fmaxf(mxB, __shfl_xor(mxB, 16));
    mxB = fmaxf(mxB, __shfl_xor(mxB, 32));
    if (__any(mxB > mrunB + 8.f)) {
      const float nm = fmaxf(mrunB, mxB);
      const float fac = __builtin_amdgcn_exp2f(mrunB - nm);
      mrunB = nm;
      lsumB *= fac;
#pragma unroll
      for (int dt = 0; dt < 4; ++dt)
#pragma unroll
        for (int r = 0; r < 4; ++r) accB[dt][r] *= fac;
    }
    float pB[4][4];
#pragma unroll
    for (int nt = 0; nt < 4; ++nt)
#pragma unroll
      for (int r = 0; r < 4; ++r) {
        pB[nt][r] = __builtin_amdgcn_exp2f(sfB[nt][r] - mrunB);
        lsumB += pB[nt][r];
      }
    i32x4 wb0, wb1;
    wb0.x = cvt_pk_bf16(pB[0][0], pB[0][1]);
    wb0.y = cvt_pk_bf16(pB[0][2], pB[0][3]);
    wb0.z = cvt_pk_bf16(pB[1][0], pB[1][1]);
    wb0.w = cvt_pk_bf16(pB[1][2], pB[1][3]);
    wb1.x = cvt_pk_bf16(pB[2][0], pB[2][1]);
    wb1.y = cvt_pk_bf16(pB[2][2], pB[2][3]);
    wb1.z = cvt_pk_bf16(pB[3][0], pB[3][1]);
    wb1.w = cvt_pk_bf16(pB[3][2], pB[3][3]);
    short8 paB0 = __builtin_bit_cast(short8, wb0);
    short8 paB1 = __builtin_bit_cast(short8, wb1);

    // ---- PV: vf shared by both q-groups ----
    __builtin_amdgcn_s_setprio(1);
#pragma unroll
    for (int dt = 0; dt < 4; ++dt) {
      accA[dt] = MFMA16(vf0[dt], paA0, accA[dt]);  // swapped: col=q, row=d
      accA[dt] = MFMA16(vf1[dt], paA1, accA[dt]);
      accB[dt] = MFMA16(vf0[dt], paB0, accB[dt]);
      accB[dt] = MFMA16(vf1[dt], paB1, accB[dt]);
    }
    __builtin_amdgcn_s_setprio(0);

    __syncthreads();  // next tile staged (vmcnt drained) + reads done
    buf ^= 1;
  }
#undef STAGE_KV

  // combine per-lane partial sums across each q-row, normalize, store
  const int b = bh >> 4, h = bh & (H - 1);
  {
    float ltot = lsumA;
    ltot += __shfl_xor(ltot, 16);
    ltot += __shfl_xor(ltot, 32);
    const float inv = 1.0f / ltot;
    const int row = q0 + lr;
#pragma unroll
    for (int dt = 0; dt < 4; ++dt) {
      us4 o;
#pragma unroll
      for (int r = 0; r < 4; ++r) o[r] = f2bf(accA[dt][r] * inv);
      *reinterpret_cast<us4*>(
          &Xb[((size_t)b * S + row) * E + h * D + dt * 16 + 4 * jj]) = o;
    }
  }
  {
    float ltot = lsumB;
    ltot += __shfl_xor(ltot, 16);
    ltot += __shfl_xor(ltot, 32);
    const float inv = 1.0f / ltot;
    const int row = q0 + 16 + lr;
#pragma unroll
    for (int dt = 0; dt < 4; ++dt) {
      us4 o;
#pragma unroll
      for (int r = 0; r < 4; ++r) o[r] = f2bf(accB[dt][r] * inv);
      *reinterpret_cast<us4*>(
          &Xb[((size_t)b * S + row) * E + h * D + dt * 16 + 4 * jj]) = o;
    }
  }
}

extern "C" void kernel_launch(void* const* d_in, const int* in_sizes, int n_in,
                              void* d_out, int out_size, void* d_ws, size_t ws_size,
                              hipStream_t stream) {
  const float* q_f = (const float*)d_in[0];
  const float* k_f = (const float*)d_in[1];
  const float* v_f = (const float*)d_in[2];
  const float* wq_f = (const float*)d_in[3];
  const float* wk_f = (const float*)d_in[4];
  const float* wv_f = (const float*)d_in[5];
  const float* wo_f = (const float*)d_in[6];

  // workspace layout (bf16 halves): 7*NE + 4*NW elements = 64 MB
  unsigned short* xq = (unsigned short*)d_ws;
  unsigned short* xk = xq + NE;
  unsigned short* xv = xk + NE;
  unsigned short* wq = xv + NE;
  unsigned short* wk = wq + NW;
  unsigned short* wv = wk + NW;
  unsigned short* wo = wv + NW;
  unsigned short* Qh = wo + NW;
  unsigned short* Kh = Qh + NE;
  unsigned short* Vt = Kh + NE;
  unsigned short* Xb = Vt + NE;

  // 1) convert inputs + weights to bf16 (2 fused launches)
  cvt_act_kernel<<<dim3(512, 3), 256, 0, stream>>>(q_f, k_f, v_f, xq, xk, xv,
                                                   (int)(NE / 4));
  cvt_w_kernel<<<dim3(256, 4), 256, 0, stream>>>(wq_f, wk_f, wv_f, wo_f, wq, wk,
                                                 wv, wo, (int)(NW / 4));

  // 2) fused Q/K/V projections (768 blocks = 3 blocks/CU)
  gemm_proj_kernel<<<dim3(M / 128, E / 128, 3), 256, 0, stream>>>(
      xq, xk, xv, wq, wk, wv, Qh, Kh, Vt);

  // 3) flash attention (32 q-rows/wave, 128-row blocks, register-only P)
  attn_kernel<<<dim3(S / 128, B * H), 256, 0, stream>>>(Qh, Kh, Vt, Xb);

  // 4) output projection (512 blocks = 2 blocks/CU, fp32 out)
  gemm_out_kernel<<<dim3(M / 128, E / 64), 256, 0, stream>>>(Xb, wo,
                                                             (float*)d_out);
}